// Round 10
// baseline (271.602 us; speedup 1.0000x reference)
//
#include <hip/hip_runtime.h>
#include <hip/hip_bf16.h>
#include <math.h>

#define BB 4
#define CC 128
#define HH 128
#define WWD 128
#define HWW 16384
#define PREC 17424  // 132*132 padded records per plane

typedef __attribute__((ext_vector_type(8))) short bf16x8;
typedef __attribute__((ext_vector_type(4))) float floatx4;
typedef __attribute__((ext_vector_type(4))) unsigned short us4;
typedef __attribute__((ext_vector_type(8))) unsigned short us8;

// tanh-form gelu: x*sigmoid(x*(1.5957691 + 0.0713548*x^2)).
__device__ __forceinline__ float gelu_fast(float v) {
  float u = v * v;
  float z = v * fmaf(0.0713548163f, u, 1.5957691216f);
  float e = __builtin_amdgcn_exp2f(-1.4426950409f * z);
  return v * __builtin_amdgcn_rcpf(1.0f + e);
}
__device__ __forceinline__ unsigned short f2us(float f) {
  union { float f; unsigned int u; } c; c.f = f;
  unsigned int u = c.u;
  return (unsigned short)((u + 0x7FFFu + ((u >> 16) & 1u)) >> 16);
}

// ---------------- Kernel PR: merged prep (zero borders + wprep + wprep2) --
// blocks 0..33: border-zero + part2-zero (k_zero body)
// blocks 34..97: w1/w2 MFMA-fragment swizzle (k_wprep body)
// blocks 98..106: conv-weight swizzle (k_wprep2 body)
__global__ __launch_bounds__(256) void k_prep(
    unsigned short* __restrict__ xp, float* __restrict__ part2,
    const float* __restrict__ w1, const float* __restrict__ w2,
    unsigned short* __restrict__ w1b, unsigned short* __restrict__ w2b,
    const float* __restrict__ offw, const float* __restrict__ dilw,
    unsigned short* __restrict__ wob, unsigned short* __restrict__ w3b) {
  int bid = blockIdx.x;
  if (bid < 34) {
    if (bid == 33) { part2[threadIdx.x] = 0.f; return; }
    int g = bid * 256 + threadIdx.x;
    if (g >= 8320) return;
    int pl = g / 1040;
    int r = g - pl * 1040;
    int yy, xx;
    if (r < 528) {                 // rows 0,1,130,131 in full
      int q = r / 132;
      yy = q < 2 ? q : 126 + q;
      xx = r - q * 132;
    } else {                       // cols 0,1,130,131 for rows 2..129
      int r2 = r - 528;
      yy = 2 + (r2 >> 2);
      int side = r2 & 3;
      xx = side < 2 ? side : 128 + side;
    }
    long rec = (long)pl * PREC + yy * 132 + xx;
    unsigned short* d = &xp[rec * 32];
    us8 z = (us8)0;
    *(us8*)&d[0] = z; *(us8*)&d[8] = z; *(us8*)&d[16] = z; *(us8*)&d[24] = z;
  } else if (bid < 98) {
    int t = (bid - 34) * 256 + threadIdx.x;
    int which = t >> 13;
    int u = t & 8191;
    int lane = u & 63;
    int ntks = u >> 6;
    int col = lane & 15, quad = lane >> 4;
    if (which == 0) {
      int nt = ntks >> 2, ks = ntks & 3;
      int n = nt * 16 + col;
      int k0 = ks * 32 + quad * 8;
      unsigned short* d = w1b + (long)u * 8;
#pragma unroll
      for (int j = 0; j < 8; j++) d[j] = f2us(w1[(long)(k0 + j) * 512 + n]);
    } else {
      int nt = ntks >> 4, ks = ntks & 15;
      int n = nt * 16 + col;
      int k0 = ks * 32 + quad * 8;
      unsigned short* d = w2b + (long)u * 8;
#pragma unroll
      for (int j = 0; j < 8; j++) d[j] = f2us(w2[(long)(k0 + j) * 128 + n]);
    }
  } else {
    int t = (bid - 98) * 256 + threadIdx.x;  // 0..2303
    if (t >= 2304) return;
    int which = t >= 1152;
    int u = t - which * 1152;
    int lane = u & 63, tn = u >> 6;          // tn = tap*2 + nt
    int col = lane & 15, quad = lane >> 4;
    int tap = tn >> 1, nt = tn & 1;
    int n = nt * 16 + col;
    const float* W = which ? dilw : offw;
    int noc = which ? 32 : 18;
    unsigned short* d = (which ? w3b : wob) + (long)(tn * 64 + lane) * 8;
#pragma unroll
    for (int j = 0; j < 8; j++)
      d[j] = (n < noc) ? f2us(W[(long)n * 288 + (quad * 8 + j) * 9 + tap]) : (unsigned short)0;
  }
}

// ---------------- Kernel P: pack padded bf16 planes (+ xt fp32 fused) -----
__global__ __launch_bounds__(256) void k_pack(
    const float* __restrict__ x, unsigned short* __restrict__ xp,
    float* __restrict__ xt) {
  __shared__ float t[64 * 33];
  int bid = blockIdx.x;            // 2048 = which(2) x b(4) x pg(256)
  int tid = threadIdx.x;
  int which = bid >> 10, b = (bid >> 8) & 3, pg = bid & 255;
  int cbase = which ? 96 : 0;
  int c = tid >> 3, g8 = tid & 7;
  const float* xpr = x + ((long)b * CC + cbase + c) * HWW + pg * 64 + g8 * 8;
  float4 v0 = *(const float4*)xpr;
  float4 v1 = *(const float4*)(xpr + 4);
  t[(g8 * 8 + 0) * 33 + c] = v0.x; t[(g8 * 8 + 1) * 33 + c] = v0.y;
  t[(g8 * 8 + 2) * 33 + c] = v0.z; t[(g8 * 8 + 3) * 33 + c] = v0.w;
  t[(g8 * 8 + 4) * 33 + c] = v1.x; t[(g8 * 8 + 5) * 33 + c] = v1.y;
  t[(g8 * 8 + 6) * 33 + c] = v1.z; t[(g8 * 8 + 7) * 33 + c] = v1.w;
  __syncthreads();
  int u = tid >> 2, q = tid & 3;
  int p = pg * 64 + u;
  int yy = p >> 7, xx = p & 127;
  long rec = (long)(which * 4 + b) * PREC + (yy + 2) * 132 + xx + 2;
  us8 o;
  float vv[8];
#pragma unroll
  for (int k = 0; k < 8; k++) {
    vv[k] = t[u * 33 + q * 8 + k];
    o[k] = f2us(vv[k]);
  }
  *(us8*)&xp[rec * 32 + q * 8] = o;
  if (which == 0) {
    float* d = xt + ((long)b * HWW + p) * 32 + q * 8;
    float4 o0, o1;
    o0.x = vv[0]; o0.y = vv[1]; o0.z = vv[2]; o0.w = vv[3];
    o1.x = vv[4]; o1.y = vv[5]; o1.z = vv[6]; o1.w = vv[7];
    *(float4*)d = o0;
    *(float4*)(d + 4) = o1;
  }
}

// ---------------- Kernel CV: merged offset-conv + dilated-conv ------------
__global__ __launch_bounds__(256) void k_conv3(
    const unsigned short* __restrict__ xp0, const unsigned short* __restrict__ wob,
    const float* __restrict__ obias, float* __restrict__ off,
    const unsigned short* __restrict__ xp1, const unsigned short* __restrict__ w3b,
    const float* __restrict__ dbias, float* __restrict__ y) {
  int bid0 = blockIdx.x;
  int tid = threadIdx.x;
  int lane = tid & 63, wv = tid >> 6;
  int row = lane & 15, quad = lane >> 4;
  int xb = wv * 32;
  if (bid0 < 512) {
    int bid = bid0;
    int b = bid >> 7, yy = bid & 127;
    const unsigned short* plane = xp0 + (long)b * PREC * 32;
    floatx4 Oa[2][2];
#pragma unroll
    for (int mt = 0; mt < 2; mt++)
#pragma unroll
      for (int nt = 0; nt < 2; nt++) Oa[mt][nt] = (floatx4)0.f;
#pragma unroll
    for (int t = 0; t < 9; t++) {
      int dy = t / 3 - 1, dx = t % 3 - 1;
      const unsigned short* rp = plane + ((long)(yy + 2 + dy) * 132 + 2 + dx + xb) * 32;
      bf16x8 A0 = *(const bf16x8*)&rp[row * 32 + quad * 8];
      bf16x8 A1 = *(const bf16x8*)&rp[(16 + row) * 32 + quad * 8];
#pragma unroll
      for (int nt = 0; nt < 2; nt++) {
        bf16x8 Bf = *(const bf16x8*)&wob[(long)((t * 2 + nt) * 64 + lane) * 8];
        Oa[0][nt] = __builtin_amdgcn_mfma_f32_16x16x32_bf16(A0, Bf, Oa[0][nt], 0, 0, 0);
        Oa[1][nt] = __builtin_amdgcn_mfma_f32_16x16x32_bf16(A1, Bf, Oa[1][nt], 0, 0, 0);
      }
    }
#pragma unroll
    for (int nt = 0; nt < 2; nt++) {
      int oc = nt * 16 + (lane & 15);
      if (oc < 18) {
        float bb = obias[oc];
#pragma unroll
        for (int mt = 0; mt < 2; mt++) {
          floatx4 v = Oa[mt][nt];
          v[0] += bb; v[1] += bb; v[2] += bb; v[3] += bb;
          long p = (long)(b * 18 + oc) * HWW + yy * 128 + xb + mt * 16 + quad * 4;
          *(floatx4*)&off[p] = v;
        }
      }
    }
  } else {
    int bid = bid0 - 512;
    int b = bid >> 7, yy = bid & 127;
    const unsigned short* plane = xp1 + (long)b * PREC * 32;
    floatx4 Oa[2][2];
#pragma unroll
    for (int mt = 0; mt < 2; mt++)
#pragma unroll
      for (int nt = 0; nt < 2; nt++) Oa[mt][nt] = (floatx4)0.f;
#pragma unroll
    for (int t = 0; t < 9; t++) {
      int dy = (t / 3 - 1) * 2, dx = (t % 3 - 1) * 2;
      const unsigned short* rp = plane + ((long)(yy + 2 + dy) * 132 + 2 + dx + xb) * 32;
      bf16x8 A0 = *(const bf16x8*)&rp[row * 32 + quad * 8];
      bf16x8 A1 = *(const bf16x8*)&rp[(16 + row) * 32 + quad * 8];
#pragma unroll
      for (int nt = 0; nt < 2; nt++) {
        bf16x8 Bf = *(const bf16x8*)&w3b[(long)((t * 2 + nt) * 64 + lane) * 8];
        Oa[0][nt] = __builtin_amdgcn_mfma_f32_16x16x32_bf16(A0, Bf, Oa[0][nt], 0, 0, 0);
        Oa[1][nt] = __builtin_amdgcn_mfma_f32_16x16x32_bf16(A1, Bf, Oa[1][nt], 0, 0, 0);
      }
    }
#pragma unroll
    for (int nt = 0; nt < 2; nt++) {
      int oc = nt * 16 + (lane & 15);
      int cp = 65 + 2 * oc;   // c = 96+oc -> (c%64)*2 + c/64
      float bb = dbias[oc];
#pragma unroll
      for (int mt = 0; mt < 2; mt++) {
        floatx4 v = Oa[mt][nt];
        v[0] += bb; v[1] += bb; v[2] += bb; v[3] += bb;
        long p = ((long)b * CC + cp) * HWW + yy * 128 + xb + mt * 16 + quad * 4;
        *(floatx4*)&y[p] = v;
      }
    }
  }
}

// ---------------- Kernel B: deformable depthwise (8 ch/thread, grid 1024) -
// Was 512 blocks = 2 blocks/CU = 8 waves/CU with a serial 9-tap gather
// chain and ~80 VGPR (acc[16]+v[16]) — latency-hiding-starved. 8 channels/
// thread halves VGPR and doubles grid -> 2x TLP. Identical total traffic;
// corner loads stay >=32 B segments. (Re-applied ALONE on the round-8 base
// for bisection — round-9 bundled this with the k_pre merge and failed.)
__global__ __launch_bounds__(256) void k_deform(
    const float* __restrict__ xt, const float* __restrict__ off,
    const float* __restrict__ dw, float* __restrict__ y) {
  __shared__ float wl[72];         // [k][8]
  int tid = threadIdx.x;
  int g = blockIdx.x * 256 + tid;
  int qh = g >> 16;                // 0..3, uniform per block
  int pix = g & 65535;
  if (tid < 72) {
    int k = tid >> 3, q = tid & 7;
    wl[k * 8 + q] = dw[(qh * 8 + q) * 9 + k];
  }
  __syncthreads();
  int b = pix >> 14, p = pix & 16383;
  int i = p >> 7, j = p & 127;
  float acc[8];
#pragma unroll
  for (int q = 0; q < 8; q++) acc[q] = 0.f;
  const float* offb = off + (long)b * 18 * HWW + p;
  const float* xb = xt + (long)b * HWW * 32 + qh * 8;
  for (int k = 0; k < 9; k++) {
    float dy = offb[(long)(2 * k) * HWW];
    float dx = offb[(long)(2 * k + 1) * HWW];
    float ys = (float)i - 1.f + (float)(k / 3) + dy;
    float xs = (float)j - 1.f + (float)(k % 3) + dx;
    float y0 = floorf(ys), x0 = floorf(xs);
    float fy = ys - y0, fx = xs - x0;
    int iy0 = (int)y0, ix0 = (int)x0;
    int iy1 = iy0 + 1, ix1 = ix0 + 1;
    float wy0 = (1.f - fy) * ((iy0 >= 0 && iy0 <= 127) ? 1.f : 0.f);
    float wy1 = fy * ((iy1 >= 0 && iy1 <= 127) ? 1.f : 0.f);
    float wx0 = (1.f - fx) * ((ix0 >= 0 && ix0 <= 127) ? 1.f : 0.f);
    float wx1 = fx * ((ix1 >= 0 && ix1 <= 127) ? 1.f : 0.f);
    int cy0 = min(max(iy0, 0), 127), cy1 = min(max(iy1, 0), 127);
    int cx0 = min(max(ix0, 0), 127), cx1 = min(max(ix1, 0), 127);
    int ci[4] = {cy0 * 128 + cx0, cy0 * 128 + cx1, cy1 * 128 + cx0, cy1 * 128 + cx1};
    float cw[4] = {wy0 * wx0, wy0 * wx1, wy1 * wx0, wy1 * wx1};
    float v[8];
#pragma unroll
    for (int q = 0; q < 8; q++) v[q] = 0.f;
#pragma unroll
    for (int cn = 0; cn < 4; cn++) {
      const float* cp = xb + (long)ci[cn] * 32;
      float wc = cw[cn];
      float4 p0 = *(const float4*)cp;
      float4 p1 = *(const float4*)(cp + 4);
      v[0] += wc * p0.x;  v[1] += wc * p0.y;  v[2] += wc * p0.z;  v[3] += wc * p0.w;
      v[4] += wc * p1.x;  v[5] += wc * p1.y;  v[6] += wc * p1.z;  v[7] += wc * p1.w;
    }
    const float* wr = &wl[k * 8];
#pragma unroll
    for (int q = 0; q < 8; q++) acc[q] += wr[q] * v[q];
  }
#pragma unroll
  for (int q = 0; q < 8; q++) {
    int cp = 2 * (qh * 8 + q);
    y[((long)b * CC + cp) * HWW + p] = acc[q];
  }
}

// ---------------- Kernel C: depthwise 7x7, LDS-tiled ----------------------
__global__ __launch_bounds__(256) void k_dw7(
    const float* __restrict__ x, const float* __restrict__ w,
    const float* __restrict__ bias, float* __restrict__ y) {
  __shared__ float tile[22 * 136];
  __shared__ float wl[49];
  __shared__ float bsh;
  int bid = blockIdx.x;
  int b = bid >> 9, m = (bid >> 3) & 63, strip = bid & 7;
  int r0 = strip * 16;
  int tid = threadIdx.x;
  const float* xp = x + ((long)b * CC + 32 + m) * HWW;
  for (int idx = tid; idx < 2948; idx += 256) {
    int rr = idx / 134;
    int cc = idx - rr * 134 - 3;
    int gy = r0 - 3 + rr;
    float v = 0.f;
    if ((unsigned)gy < 128u && (unsigned)cc < 128u) v = xp[gy * 128 + cc];
    tile[rr * 136 + cc + 3] = v;
  }
  if (tid < 49) wl[tid] = w[m * 49 + tid];
  if (tid == 64) bsh = bias[m];
  __syncthreads();
  int j = tid & 127, s = tid >> 7;
  float acc[8];
#pragma unroll
  for (int o = 0; o < 8; o++) acc[o] = bsh;
#pragma unroll
  for (int kx = 0; kx < 7; kx++) {
#pragma unroll
    for (int rr = 0; rr < 14; rr++) {
      float v = tile[(s * 8 + rr) * 136 + j + kx];
      int olo = rr - 6 > 0 ? rr - 6 : 0;
      int ohi = rr < 7 ? rr : 7;
#pragma unroll
      for (int o = 0; o < 8; o++) {
        if (o >= olo && o <= ohi) acc[o] += v * wl[(rr - o) * 7 + kx];
      }
    }
  }
  int c = 32 + m;
  int cp = (c & 63) * 2 + (c >> 6);
  float* yp = y + ((long)b * CC + cp) * HWW;
#pragma unroll
  for (int o = 0; o < 8; o++) {
    yp[(r0 + s * 8 + o) * 128 + j] = acc[o];
  }
}

// ---------------- stats (bn1): stage 1 only (stage 2 fused into k_mlp) ----
__global__ __launch_bounds__(256) void k_stats1(
    const float* __restrict__ buf, float* __restrict__ part) {
  __shared__ float sh[256], sh2[256];
  int c = blockIdx.x >> 2, b = blockIdx.x & 3;
  int tid = threadIdx.x;
  const float* p = buf + ((long)b * CC + c) * HWW;
  float s = 0.f, s2 = 0.f;
  for (int it = 0; it < 16; it++) {
    float4 v = *(const float4*)(p + (it * 256 + tid) * 4);
    s += v.x + v.y + v.z + v.w;
    s2 += v.x * v.x + v.y * v.y + v.z * v.z + v.w * v.w;
  }
  sh[tid] = s; sh2[tid] = s2;
  __syncthreads();
  for (int o = 128; o > 0; o >>= 1) {
    if (tid < o) { sh[tid] += sh[tid + o]; sh2[tid] += sh2[tid + o]; }
    __syncthreads();
  }
  if (tid == 0) {
    part[blockIdx.x * 2] = sh[0];
    part[blockIdx.x * 2 + 1] = sh2[0];
  }
}

// ---------------- Kernel F: BN1 + MLP via bf16 MFMA (H^T + fast gelu) -----
// GEMM1 computes H^T so gelu'd writes to Hs[tok][h] are contiguous (us4).
// Per-chunk barriers: measured removing them costs ~12 µs (wave phase
// drift). bn1 stage-2 computed per-block in the preamble; bn2 partials in
// epilogue. NOTE: 64-token tiles, register H-handoff, and split-streaming
// MLP all measured SLOWER (83/96/305/328 µs vs 68-70). This exact structure
// is the empirical optimum; schedule-fragile — do not perturb.
__global__ __launch_bounds__(256, 2) void k_mlp_mfma(
    const float* __restrict__ y, const float* __restrict__ part,
    const float* __restrict__ g1, const float* __restrict__ b1n,
    const unsigned short* __restrict__ w1b, const float* __restrict__ b1,
    const unsigned short* __restrict__ w2b, const float* __restrict__ b2,
    float* __restrict__ tmid, float* __restrict__ part2) {
  __shared__ unsigned short At[128 * 136];
  __shared__ unsigned short Hs[4 * 32 * 72];
  __shared__ float scs[128], shs[128];
  __shared__ float ps[128], ps2[128];
  int tid = threadIdx.x;
  int lane = tid & 63, wv = tid >> 6;
  int row = lane & 15, quad = lane >> 4;
  int n0 = blockIdx.x * 128;
  int b = n0 >> 14;
  long base = (long)b * CC * HWW + (n0 & 16383);
  if (tid < 128) {
    float s = 0.f, s2 = 0.f;
#pragma unroll
    for (int bq = 0; bq < 4; bq++) {
      s  += part[(tid * 4 + bq) * 2];
      s2 += part[(tid * 4 + bq) * 2 + 1];
    }
    float mu = s * (1.f / 65536.f);
    float var = s2 * (1.f / 65536.f) - mu * mu;
    float sc = rsqrtf(var + 1e-5f) * g1[tid];
    scs[tid] = sc;
    shs[tid] = b1n[tid] - mu * sc;
    ps[tid] = 0.f; ps2[tid] = 0.f;
  }
  __syncthreads();
  for (int it = 0; it < 16; it++) {
    int u = it * 256 + tid;
    int tok = u & 127, cg = u >> 7;
    us4 wvv;
#pragma unroll
    for (int r = 0; r < 4; r++) {
      int c = cg * 4 + r;
      float v = y[base + (long)c * HWW + tok];
      wvv[r] = f2us(v * scs[c] + shs[c]);
    }
    *(us4*)&At[tok * 136 + cg * 4] = wvv;
  }
  __syncthreads();
  bf16x8 Af[2][4];
#pragma unroll
  for (int mt = 0; mt < 2; mt++)
#pragma unroll
    for (int ks = 0; ks < 4; ks++)
      Af[mt][ks] = *(const bf16x8*)&At[(wv * 32 + mt * 16 + row) * 136 + ks * 32 + quad * 8];

  floatx4 Oa[2][8];
#pragma unroll
  for (int mt = 0; mt < 2; mt++)
#pragma unroll
    for (int nt = 0; nt < 8; nt++) Oa[mt][nt] = (floatx4)0.f;

  const int wvb = wv * 32 * 72;
  for (int ch = 0; ch < 8; ch++) {
    // GEMM1 (H^T): M = 64 hidden (4 tiles), N = 32 tokens (2 tiles)
    floatx4 Ha[4][2];
#pragma unroll
    for (int nt = 0; nt < 4; nt++)
#pragma unroll
      for (int mt = 0; mt < 2; mt++) Ha[nt][mt] = (floatx4)0.f;
#pragma unroll
    for (int nt = 0; nt < 4; nt++) {
      int ht = ch * 4 + nt;
#pragma unroll
      for (int ks = 0; ks < 4; ks++) {
        bf16x8 Wf = *(const bf16x8*)&w1b[(long)(((ht * 4 + ks) << 6) + lane) * 8];
        Ha[nt][0] = __builtin_amdgcn_mfma_f32_16x16x32_bf16(Wf, Af[0][ks], Ha[nt][0], 0, 0, 0);
        Ha[nt][1] = __builtin_amdgcn_mfma_f32_16x16x32_bf16(Wf, Af[1][ks], Ha[nt][1], 0, 0, 0);
      }
    }
    // epilogue: h = nt*16 + quad*4 + r (contiguous in r), tok = mt*16 + row
#pragma unroll
    for (int nt = 0; nt < 4; nt++) {
      float4 bb = *(const float4*)&b1[ch * 64 + nt * 16 + quad * 4];
#pragma unroll
      for (int mt = 0; mt < 2; mt++) {
        us4 hv;
        hv[0] = f2us(gelu_fast(Ha[nt][mt][0] + bb.x));
        hv[1] = f2us(gelu_fast(Ha[nt][mt][1] + bb.y));
        hv[2] = f2us(gelu_fast(Ha[nt][mt][2] + bb.z));
        hv[3] = f2us(gelu_fast(Ha[nt][mt][3] + bb.w));
        *(us4*)&Hs[wvb + (mt * 16 + row) * 72 + nt * 16 + quad * 4] = hv;
      }
    }
    __syncthreads();  // phase-lock waves (scheduling aid; Hs is per-wave)
    // GEMM2: O += H[32 tok x 64 h] x W2[64 h x 128 c]
    bf16x8 A2[2][2];
#pragma unroll
    for (int mt = 0; mt < 2; mt++)
#pragma unroll
      for (int ks = 0; ks < 2; ks++)
        A2[mt][ks] = *(const bf16x8*)&Hs[wvb + (mt * 16 + row) * 72 + ks * 32 + quad * 8];
#pragma unroll
    for (int nt = 0; nt < 8; nt++) {
#pragma unroll
      for (int ks = 0; ks < 2; ks++) {
        bf16x8 Bf = *(const bf16x8*)&w2b[(long)(((nt * 16 + ch * 2 + ks) << 6) + lane) * 8];
        Oa[0][nt] = __builtin_amdgcn_mfma_f32_16x16x32_bf16(A2[0][ks], Bf, Oa[0][nt], 0, 0, 0);
        Oa[1][nt] = __builtin_amdgcn_mfma_f32_16x16x32_bf16(A2[1][ks], Bf, Oa[1][nt], 0, 0, 0);
      }
    }
    __syncthreads();
  }
  // final epilogue: +b2, store [c][tok] fp32, accumulate bn2 partials
#pragma unroll
  for (int nt = 0; nt < 8; nt++) {
    int c = nt * 16 + row;
    float bb = b2[c];
    long op = base + (long)c * HWW + wv * 32 + quad * 4;
    float s = 0.f, s2 = 0.f;
#pragma unroll
    for (int mt = 0; mt < 2; mt++) {
      floatx4 vv = Oa[mt][nt];
      vv[0] += bb; vv[1] += bb; vv[2] += bb; vv[3] += bb;
      *(floatx4*)&tmid[op + mt * 16] = vv;
      s += vv[0] + vv[1] + vv[2] + vv[3];
      s2 += vv[0] * vv[0] + vv[1] * vv[1] + vv[2] * vv[2] + vv[3] * vv[3];
    }
    atomicAdd(&ps[c], s);
    atomicAdd(&ps2[c], s2);
  }
  __syncthreads();
  if (tid < 128) {
    atomicAdd(&part2[tid], ps[tid]);
    atomicAdd(&part2[128 + tid], ps2[tid]);
  }
}

// ---------------- Kernel H: bn2 + residual + gelu (stats2b fused) ---------
__global__ __launch_bounds__(256) void k_final(
    const float* __restrict__ x, const float* __restrict__ part2,
    const float* __restrict__ g2, const float* __restrict__ b2n,
    float* __restrict__ out) {
  long e4 = (long)blockIdx.x * 256 + threadIdx.x;
  int c = (int)((e4 >> 12) & 127);
  float mu = part2[c] * (1.f / 65536.f);
  float var = part2[128 + c] * (1.f / 65536.f) - mu * mu;
  float sc = rsqrtf(var + 1e-5f) * g2[c];
  float sh = b2n[c] - mu * sc;
  float4 o = *(float4*)&out[e4 * 4];
  float4 xv = *(const float4*)&x[e4 * 4];
  o.x = gelu_fast(xv.x + o.x * sc + sh);
  o.y = gelu_fast(xv.y + o.y * sc + sh);
  o.z = gelu_fast(xv.z + o.z * sc + sh);
  o.w = gelu_fast(xv.w + o.w * sc + sh);
  *(float4*)&out[e4 * 4] = o;
}

extern "C" void kernel_launch(void* const* d_in, const int* in_sizes, int n_in,
                              void* d_out, int out_size, void* d_ws, size_t ws_size,
                              hipStream_t stream) {
  const float* x        = (const float*)d_in[0];
  const float* offset_w = (const float*)d_in[1];
  const float* offset_b = (const float*)d_in[2];
  const float* deform_w = (const float*)d_in[3];
  const float* dw_w     = (const float*)d_in[4];
  const float* dw_b     = (const float*)d_in[5];
  const float* dw2_w    = (const float*)d_in[6];
  const float* dw2_b    = (const float*)d_in[7];
  const float* bn1_g    = (const float*)d_in[8];
  const float* bn1_b    = (const float*)d_in[9];
  const float* w1       = (const float*)d_in[10];
  const float* b1       = (const float*)d_in[11];
  const float* w2       = (const float*)d_in[12];
  const float* b2       = (const float*)d_in[13];
  const float* bn2_g    = (const float*)d_in[14];
  const float* bn2_b    = (const float*)d_in[15];
  float* out = (float*)d_out;

  float* ws    = (float*)d_ws;
  float* off   = ws;                       // 1,179,648 f
  float* ybuf  = ws + 1179648;             // 8,388,608 f
  unsigned short* w1b = (unsigned short*)(ws + 9568768);  // 65,536 us
  unsigned short* w2b = (unsigned short*)(ws + 9601536);  // 65,536 us
  float* part  = ws + 9634304;             // 1,024 f (bn1 partials)
  float* xt    = ws + 9635328;             // 2,097,152 f
  unsigned short* wob = (unsigned short*)(ws + 11732480); // 9,216 us
  unsigned short* w3b = (unsigned short*)(ws + 11737088); // 9,216 us
  unsigned short* xp  = (unsigned short*)(ws + 11741696); // 4,460,544 us
  unsigned short* xp0 = xp;
  unsigned short* xp1 = xp + (long)4 * PREC * 32;
  float* part2 = ws + 13971968;            // 256 f (atomic bn2 accumulators)
  float* tmid  = out;

  k_prep<<<107, 256, 0, stream>>>(xp, part2, w1, w2, w1b, w2b,
                                  offset_w, dw2_w, wob, w3b);
  k_pack<<<2048, 256, 0, stream>>>(x, xp, xt);
  k_conv3<<<1024, 256, 0, stream>>>(xp0, wob, offset_b, off, xp1, w3b, dw2_b, ybuf);
  k_deform<<<1024, 256, 0, stream>>>(xt, off, deform_w, ybuf);
  k_dw7<<<2048, 256, 0, stream>>>(x, dw_w, dw_b, ybuf);
  k_stats1<<<512, 256, 0, stream>>>(ybuf, part);
  k_mlp_mfma<<<512, 256, 0, stream>>>(ybuf, part, bn1_g, bn1_b, w1b, b1, w2b, b2, tmid, part2);
  k_final<<<8192, 256, 0, stream>>>(x, part2, bn2_g, bn2_b, out);
}

// Round 11
// 263.917 us; speedup vs baseline: 1.0291x; 1.0291x over previous
//
#include <hip/hip_runtime.h>
#include <hip/hip_bf16.h>
#include <math.h>

#define BB 4
#define CC 128
#define HH 128
#define WWD 128
#define HWW 16384
#define PREC 17424  // 132*132 padded records per plane

typedef __attribute__((ext_vector_type(8))) short bf16x8;
typedef __attribute__((ext_vector_type(4))) float floatx4;
typedef __attribute__((ext_vector_type(4))) unsigned short us4;
typedef __attribute__((ext_vector_type(8))) unsigned short us8;

// tanh-form gelu: x*sigmoid(x*(1.5957691 + 0.0713548*x^2)).
__device__ __forceinline__ float gelu_fast(float v) {
  float u = v * v;
  float z = v * fmaf(0.0713548163f, u, 1.5957691216f);
  float e = __builtin_amdgcn_exp2f(-1.4426950409f * z);
  return v * __builtin_amdgcn_rcpf(1.0f + e);
}
__device__ __forceinline__ unsigned short f2us(float f) {
  union { float f; unsigned int u; } c; c.f = f;
  unsigned int u = c.u;
  return (unsigned short)((u + 0x7FFFu + ((u >> 16) & 1u)) >> 16);
}

// ---------------- Kernel PR: merged prep (zero borders + wprep + wprep2) --
// blocks 0..33: border-zero + part2-zero (k_zero body)
// blocks 34..97: w1/w2 MFMA-fragment swizzle (k_wprep body)
// blocks 98..106: conv-weight swizzle (k_wprep2 body)
// NOTE: no LDS, no barriers — the round-9 attempt to also fold k_pack/k_dw7
// (LDS-union across branches) FAILED correctness; do not re-merge those.
__global__ __launch_bounds__(256) void k_prep(
    unsigned short* __restrict__ xp, float* __restrict__ part2,
    const float* __restrict__ w1, const float* __restrict__ w2,
    unsigned short* __restrict__ w1b, unsigned short* __restrict__ w2b,
    const float* __restrict__ offw, const float* __restrict__ dilw,
    unsigned short* __restrict__ wob, unsigned short* __restrict__ w3b) {
  int bid = blockIdx.x;
  if (bid < 34) {
    if (bid == 33) { part2[threadIdx.x] = 0.f; return; }
    int g = bid * 256 + threadIdx.x;
    if (g >= 8320) return;
    int pl = g / 1040;
    int r = g - pl * 1040;
    int yy, xx;
    if (r < 528) {                 // rows 0,1,130,131 in full
      int q = r / 132;
      yy = q < 2 ? q : 126 + q;
      xx = r - q * 132;
    } else {                       // cols 0,1,130,131 for rows 2..129
      int r2 = r - 528;
      yy = 2 + (r2 >> 2);
      int side = r2 & 3;
      xx = side < 2 ? side : 128 + side;
    }
    long rec = (long)pl * PREC + yy * 132 + xx;
    unsigned short* d = &xp[rec * 32];
    us8 z = (us8)0;
    *(us8*)&d[0] = z; *(us8*)&d[8] = z; *(us8*)&d[16] = z; *(us8*)&d[24] = z;
  } else if (bid < 98) {
    int t = (bid - 34) * 256 + threadIdx.x;
    int which = t >> 13;
    int u = t & 8191;
    int lane = u & 63;
    int ntks = u >> 6;
    int col = lane & 15, quad = lane >> 4;
    if (which == 0) {
      int nt = ntks >> 2, ks = ntks & 3;
      int n = nt * 16 + col;
      int k0 = ks * 32 + quad * 8;
      unsigned short* d = w1b + (long)u * 8;
#pragma unroll
      for (int j = 0; j < 8; j++) d[j] = f2us(w1[(long)(k0 + j) * 512 + n]);
    } else {
      int nt = ntks >> 4, ks = ntks & 15;
      int n = nt * 16 + col;
      int k0 = ks * 32 + quad * 8;
      unsigned short* d = w2b + (long)u * 8;
#pragma unroll
      for (int j = 0; j < 8; j++) d[j] = f2us(w2[(long)(k0 + j) * 128 + n]);
    }
  } else {
    int t = (bid - 98) * 256 + threadIdx.x;  // 0..2303
    if (t >= 2304) return;
    int which = t >= 1152;
    int u = t - which * 1152;
    int lane = u & 63, tn = u >> 6;          // tn = tap*2 + nt
    int col = lane & 15, quad = lane >> 4;
    int tap = tn >> 1, nt = tn & 1;
    int n = nt * 16 + col;
    const float* W = which ? dilw : offw;
    int noc = which ? 32 : 18;
    unsigned short* d = (which ? w3b : wob) + (long)(tn * 64 + lane) * 8;
#pragma unroll
    for (int j = 0; j < 8; j++)
      d[j] = (n < noc) ? f2us(W[(long)n * 288 + (quad * 8 + j) * 9 + tap]) : (unsigned short)0;
  }
}

// ---------------- Kernel P: pack padded bf16 planes (+ xt fp32 fused) -----
__global__ __launch_bounds__(256) void k_pack(
    const float* __restrict__ x, unsigned short* __restrict__ xp,
    float* __restrict__ xt) {
  __shared__ float t[64 * 33];
  int bid = blockIdx.x;            // 2048 = which(2) x b(4) x pg(256)
  int tid = threadIdx.x;
  int which = bid >> 10, b = (bid >> 8) & 3, pg = bid & 255;
  int cbase = which ? 96 : 0;
  int c = tid >> 3, g8 = tid & 7;
  const float* xpr = x + ((long)b * CC + cbase + c) * HWW + pg * 64 + g8 * 8;
  float4 v0 = *(const float4*)xpr;
  float4 v1 = *(const float4*)(xpr + 4);
  t[(g8 * 8 + 0) * 33 + c] = v0.x; t[(g8 * 8 + 1) * 33 + c] = v0.y;
  t[(g8 * 8 + 2) * 33 + c] = v0.z; t[(g8 * 8 + 3) * 33 + c] = v0.w;
  t[(g8 * 8 + 4) * 33 + c] = v1.x; t[(g8 * 8 + 5) * 33 + c] = v1.y;
  t[(g8 * 8 + 6) * 33 + c] = v1.z; t[(g8 * 8 + 7) * 33 + c] = v1.w;
  __syncthreads();
  int u = tid >> 2, q = tid & 3;
  int p = pg * 64 + u;
  int yy = p >> 7, xx = p & 127;
  long rec = (long)(which * 4 + b) * PREC + (yy + 2) * 132 + xx + 2;
  us8 o;
  float vv[8];
#pragma unroll
  for (int k = 0; k < 8; k++) {
    vv[k] = t[u * 33 + q * 8 + k];
    o[k] = f2us(vv[k]);
  }
  *(us8*)&xp[rec * 32 + q * 8] = o;
  if (which == 0) {
    float* d = xt + ((long)b * HWW + p) * 32 + q * 8;
    float4 o0, o1;
    o0.x = vv[0]; o0.y = vv[1]; o0.z = vv[2]; o0.w = vv[3];
    o1.x = vv[4]; o1.y = vv[5]; o1.z = vv[6]; o1.w = vv[7];
    *(float4*)d = o0;
    *(float4*)(d + 4) = o1;
  }
}

// ---------------- Kernel CV: merged offset-conv + dilated-conv ------------
__global__ __launch_bounds__(256) void k_conv3(
    const unsigned short* __restrict__ xp0, const unsigned short* __restrict__ wob,
    const float* __restrict__ obias, float* __restrict__ off,
    const unsigned short* __restrict__ xp1, const unsigned short* __restrict__ w3b,
    const float* __restrict__ dbias, float* __restrict__ y) {
  int bid0 = blockIdx.x;
  int tid = threadIdx.x;
  int lane = tid & 63, wv = tid >> 6;
  int row = lane & 15, quad = lane >> 4;
  int xb = wv * 32;
  if (bid0 < 512) {
    int bid = bid0;
    int b = bid >> 7, yy = bid & 127;
    const unsigned short* plane = xp0 + (long)b * PREC * 32;
    floatx4 Oa[2][2];
#pragma unroll
    for (int mt = 0; mt < 2; mt++)
#pragma unroll
      for (int nt = 0; nt < 2; nt++) Oa[mt][nt] = (floatx4)0.f;
#pragma unroll
    for (int t = 0; t < 9; t++) {
      int dy = t / 3 - 1, dx = t % 3 - 1;
      const unsigned short* rp = plane + ((long)(yy + 2 + dy) * 132 + 2 + dx + xb) * 32;
      bf16x8 A0 = *(const bf16x8*)&rp[row * 32 + quad * 8];
      bf16x8 A1 = *(const bf16x8*)&rp[(16 + row) * 32 + quad * 8];
#pragma unroll
      for (int nt = 0; nt < 2; nt++) {
        bf16x8 Bf = *(const bf16x8*)&wob[(long)((t * 2 + nt) * 64 + lane) * 8];
        Oa[0][nt] = __builtin_amdgcn_mfma_f32_16x16x32_bf16(A0, Bf, Oa[0][nt], 0, 0, 0);
        Oa[1][nt] = __builtin_amdgcn_mfma_f32_16x16x32_bf16(A1, Bf, Oa[1][nt], 0, 0, 0);
      }
    }
#pragma unroll
    for (int nt = 0; nt < 2; nt++) {
      int oc = nt * 16 + (lane & 15);
      if (oc < 18) {
        float bb = obias[oc];
#pragma unroll
        for (int mt = 0; mt < 2; mt++) {
          floatx4 v = Oa[mt][nt];
          v[0] += bb; v[1] += bb; v[2] += bb; v[3] += bb;
          long p = (long)(b * 18 + oc) * HWW + yy * 128 + xb + mt * 16 + quad * 4;
          *(floatx4*)&off[p] = v;
        }
      }
    }
  } else {
    int bid = bid0 - 512;
    int b = bid >> 7, yy = bid & 127;
    const unsigned short* plane = xp1 + (long)b * PREC * 32;
    floatx4 Oa[2][2];
#pragma unroll
    for (int mt = 0; mt < 2; mt++)
#pragma unroll
      for (int nt = 0; nt < 2; nt++) Oa[mt][nt] = (floatx4)0.f;
#pragma unroll
    for (int t = 0; t < 9; t++) {
      int dy = (t / 3 - 1) * 2, dx = (t % 3 - 1) * 2;
      const unsigned short* rp = plane + ((long)(yy + 2 + dy) * 132 + 2 + dx + xb) * 32;
      bf16x8 A0 = *(const bf16x8*)&rp[row * 32 + quad * 8];
      bf16x8 A1 = *(const bf16x8*)&rp[(16 + row) * 32 + quad * 8];
#pragma unroll
      for (int nt = 0; nt < 2; nt++) {
        bf16x8 Bf = *(const bf16x8*)&w3b[(long)((t * 2 + nt) * 64 + lane) * 8];
        Oa[0][nt] = __builtin_amdgcn_mfma_f32_16x16x32_bf16(A0, Bf, Oa[0][nt], 0, 0, 0);
        Oa[1][nt] = __builtin_amdgcn_mfma_f32_16x16x32_bf16(A1, Bf, Oa[1][nt], 0, 0, 0);
      }
    }
#pragma unroll
    for (int nt = 0; nt < 2; nt++) {
      int oc = nt * 16 + (lane & 15);
      int cp = 65 + 2 * oc;   // c = 96+oc -> (c%64)*2 + c/64
      float bb = dbias[oc];
#pragma unroll
      for (int mt = 0; mt < 2; mt++) {
        floatx4 v = Oa[mt][nt];
        v[0] += bb; v[1] += bb; v[2] += bb; v[3] += bb;
        long p = ((long)b * CC + cp) * HWW + yy * 128 + xb + mt * 16 + quad * 4;
        *(floatx4*)&y[p] = v;
      }
    }
  }
}

// ---------------- Kernel B: deformable depthwise, channels-last gathers ---
// 16 ch/thread, grid 512. Round-10 measured the 8-ch/grid-1024 variant
// SLOWER (+6 µs): halving channels doubles the per-pixel offset-read and
// bilinear-weight duplication (4 groups instead of 2). Keep 16-ch.
__global__ __launch_bounds__(256) void k_deform(
    const float* __restrict__ xt, const float* __restrict__ off,
    const float* __restrict__ dw, float* __restrict__ y) {
  __shared__ float wl[144];        // [k][16]
  int tid = threadIdx.x;
  int g = blockIdx.x * 256 + tid;
  int hf = g >> 16;                // uniform per block
  int pix = g & 65535;
  if (tid < 144) {
    int k = tid >> 4, q = tid & 15;
    wl[k * 16 + q] = dw[(hf * 16 + q) * 9 + k];
  }
  __syncthreads();
  int b = pix >> 14, p = pix & 16383;
  int i = p >> 7, j = p & 127;
  float acc[16];
#pragma unroll
  for (int q = 0; q < 16; q++) acc[q] = 0.f;
  const float* offb = off + (long)b * 18 * HWW + p;
  const float* xb = xt + (long)b * HWW * 32 + hf * 16;
  for (int k = 0; k < 9; k++) {
    float dy = offb[(long)(2 * k) * HWW];
    float dx = offb[(long)(2 * k + 1) * HWW];
    float ys = (float)i - 1.f + (float)(k / 3) + dy;
    float xs = (float)j - 1.f + (float)(k % 3) + dx;
    float y0 = floorf(ys), x0 = floorf(xs);
    float fy = ys - y0, fx = xs - x0;
    int iy0 = (int)y0, ix0 = (int)x0;
    int iy1 = iy0 + 1, ix1 = ix0 + 1;
    float wy0 = (1.f - fy) * ((iy0 >= 0 && iy0 <= 127) ? 1.f : 0.f);
    float wy1 = fy * ((iy1 >= 0 && iy1 <= 127) ? 1.f : 0.f);
    float wx0 = (1.f - fx) * ((ix0 >= 0 && ix0 <= 127) ? 1.f : 0.f);
    float wx1 = fx * ((ix1 >= 0 && ix1 <= 127) ? 1.f : 0.f);
    int cy0 = min(max(iy0, 0), 127), cy1 = min(max(iy1, 0), 127);
    int cx0 = min(max(ix0, 0), 127), cx1 = min(max(ix1, 0), 127);
    int ci[4] = {cy0 * 128 + cx0, cy0 * 128 + cx1, cy1 * 128 + cx0, cy1 * 128 + cx1};
    float cw[4] = {wy0 * wx0, wy0 * wx1, wy1 * wx0, wy1 * wx1};
    float v[16];
#pragma unroll
    for (int q = 0; q < 16; q++) v[q] = 0.f;
#pragma unroll
    for (int cn = 0; cn < 4; cn++) {
      const float* cp = xb + (long)ci[cn] * 32;
      float wc = cw[cn];
      float4 p0 = *(const float4*)cp;
      float4 p1 = *(const float4*)(cp + 4);
      float4 p2 = *(const float4*)(cp + 8);
      float4 p3 = *(const float4*)(cp + 12);
      v[0] += wc * p0.x;  v[1] += wc * p0.y;  v[2] += wc * p0.z;  v[3] += wc * p0.w;
      v[4] += wc * p1.x;  v[5] += wc * p1.y;  v[6] += wc * p1.z;  v[7] += wc * p1.w;
      v[8] += wc * p2.x;  v[9] += wc * p2.y;  v[10] += wc * p2.z; v[11] += wc * p2.w;
      v[12] += wc * p3.x; v[13] += wc * p3.y; v[14] += wc * p3.z; v[15] += wc * p3.w;
    }
    const float* wr = &wl[k * 16];
#pragma unroll
    for (int q = 0; q < 16; q++) acc[q] += wr[q] * v[q];
  }
#pragma unroll
  for (int q = 0; q < 16; q++) {
    int cp = 2 * (hf * 16 + q);
    y[((long)b * CC + cp) * HWW + p] = acc[q];
  }
}

// ---------------- Kernel C: depthwise 7x7, LDS-tiled ----------------------
__global__ __launch_bounds__(256) void k_dw7(
    const float* __restrict__ x, const float* __restrict__ w,
    const float* __restrict__ bias, float* __restrict__ y) {
  __shared__ float tile[22 * 136];
  __shared__ float wl[49];
  __shared__ float bsh;
  int bid = blockIdx.x;
  int b = bid >> 9, m = (bid >> 3) & 63, strip = bid & 7;
  int r0 = strip * 16;
  int tid = threadIdx.x;
  const float* xp = x + ((long)b * CC + 32 + m) * HWW;
  for (int idx = tid; idx < 2948; idx += 256) {
    int rr = idx / 134;
    int cc = idx - rr * 134 - 3;
    int gy = r0 - 3 + rr;
    float v = 0.f;
    if ((unsigned)gy < 128u && (unsigned)cc < 128u) v = xp[gy * 128 + cc];
    tile[rr * 136 + cc + 3] = v;
  }
  if (tid < 49) wl[tid] = w[m * 49 + tid];
  if (tid == 64) bsh = bias[m];
  __syncthreads();
  int j = tid & 127, s = tid >> 7;
  float acc[8];
#pragma unroll
  for (int o = 0; o < 8; o++) acc[o] = bsh;
#pragma unroll
  for (int kx = 0; kx < 7; kx++) {
#pragma unroll
    for (int rr = 0; rr < 14; rr++) {
      float v = tile[(s * 8 + rr) * 136 + j + kx];
      int olo = rr - 6 > 0 ? rr - 6 : 0;
      int ohi = rr < 7 ? rr : 7;
#pragma unroll
      for (int o = 0; o < 8; o++) {
        if (o >= olo && o <= ohi) acc[o] += v * wl[(rr - o) * 7 + kx];
      }
    }
  }
  int c = 32 + m;
  int cp = (c & 63) * 2 + (c >> 6);
  float* yp = y + ((long)b * CC + cp) * HWW;
#pragma unroll
  for (int o = 0; o < 8; o++) {
    yp[(r0 + s * 8 + o) * 128 + j] = acc[o];
  }
}

// ---------------- stats (bn1): stage 1 only (stage 2 fused into k_mlp) ----
__global__ __launch_bounds__(256) void k_stats1(
    const float* __restrict__ buf, float* __restrict__ part) {
  __shared__ float sh[256], sh2[256];
  int c = blockIdx.x >> 2, b = blockIdx.x & 3;
  int tid = threadIdx.x;
  const float* p = buf + ((long)b * CC + c) * HWW;
  float s = 0.f, s2 = 0.f;
  for (int it = 0; it < 16; it++) {
    float4 v = *(const float4*)(p + (it * 256 + tid) * 4);
    s += v.x + v.y + v.z + v.w;
    s2 += v.x * v.x + v.y * v.y + v.z * v.z + v.w * v.w;
  }
  sh[tid] = s; sh2[tid] = s2;
  __syncthreads();
  for (int o = 128; o > 0; o >>= 1) {
    if (tid < o) { sh[tid] += sh[tid + o]; sh2[tid] += sh2[tid + o]; }
    __syncthreads();
  }
  if (tid == 0) {
    part[blockIdx.x * 2] = sh[0];
    part[blockIdx.x * 2 + 1] = sh2[0];
  }
}

// ---------------- Kernel F: BN1 + MLP via bf16 MFMA (H^T + fast gelu) -----
// GEMM1 computes H^T so gelu'd writes to Hs[tok][h] are contiguous (us4).
// Per-chunk barriers: measured removing them costs ~12 µs (wave phase
// drift). bn1 stage-2 computed per-block in the preamble; bn2 partials in
// epilogue. NOTE: 64-token tiles, register H-handoff, and split-streaming
// MLP all measured SLOWER (83/96/305/328 µs vs 68-70). This exact structure
// is the empirical optimum; schedule-fragile — do not perturb.
__global__ __launch_bounds__(256, 2) void k_mlp_mfma(
    const float* __restrict__ y, const float* __restrict__ part,
    const float* __restrict__ g1, const float* __restrict__ b1n,
    const unsigned short* __restrict__ w1b, const float* __restrict__ b1,
    const unsigned short* __restrict__ w2b, const float* __restrict__ b2,
    float* __restrict__ tmid, float* __restrict__ part2) {
  __shared__ unsigned short At[128 * 136];
  __shared__ unsigned short Hs[4 * 32 * 72];
  __shared__ float scs[128], shs[128];
  __shared__ float ps[128], ps2[128];
  int tid = threadIdx.x;
  int lane = tid & 63, wv = tid >> 6;
  int row = lane & 15, quad = lane >> 4;
  int n0 = blockIdx.x * 128;
  int b = n0 >> 14;
  long base = (long)b * CC * HWW + (n0 & 16383);
  if (tid < 128) {
    float s = 0.f, s2 = 0.f;
#pragma unroll
    for (int bq = 0; bq < 4; bq++) {
      s  += part[(tid * 4 + bq) * 2];
      s2 += part[(tid * 4 + bq) * 2 + 1];
    }
    float mu = s * (1.f / 65536.f);
    float var = s2 * (1.f / 65536.f) - mu * mu;
    float sc = rsqrtf(var + 1e-5f) * g1[tid];
    scs[tid] = sc;
    shs[tid] = b1n[tid] - mu * sc;
    ps[tid] = 0.f; ps2[tid] = 0.f;
  }
  __syncthreads();
  for (int it = 0; it < 16; it++) {
    int u = it * 256 + tid;
    int tok = u & 127, cg = u >> 7;
    us4 wvv;
#pragma unroll
    for (int r = 0; r < 4; r++) {
      int c = cg * 4 + r;
      float v = y[base + (long)c * HWW + tok];
      wvv[r] = f2us(v * scs[c] + shs[c]);
    }
    *(us4*)&At[tok * 136 + cg * 4] = wvv;
  }
  __syncthreads();
  bf16x8 Af[2][4];
#pragma unroll
  for (int mt = 0; mt < 2; mt++)
#pragma unroll
    for (int ks = 0; ks < 4; ks++)
      Af[mt][ks] = *(const bf16x8*)&At[(wv * 32 + mt * 16 + row) * 136 + ks * 32 + quad * 8];

  floatx4 Oa[2][8];
#pragma unroll
  for (int mt = 0; mt < 2; mt++)
#pragma unroll
    for (int nt = 0; nt < 8; nt++) Oa[mt][nt] = (floatx4)0.f;

  const int wvb = wv * 32 * 72;
  for (int ch = 0; ch < 8; ch++) {
    // GEMM1 (H^T): M = 64 hidden (4 tiles), N = 32 tokens (2 tiles)
    floatx4 Ha[4][2];
#pragma unroll
    for (int nt = 0; nt < 4; nt++)
#pragma unroll
      for (int mt = 0; mt < 2; mt++) Ha[nt][mt] = (floatx4)0.f;
#pragma unroll
    for (int nt = 0; nt < 4; nt++) {
      int ht = ch * 4 + nt;
#pragma unroll
      for (int ks = 0; ks < 4; ks++) {
        bf16x8 Wf = *(const bf16x8*)&w1b[(long)(((ht * 4 + ks) << 6) + lane) * 8];
        Ha[nt][0] = __builtin_amdgcn_mfma_f32_16x16x32_bf16(Wf, Af[0][ks], Ha[nt][0], 0, 0, 0);
        Ha[nt][1] = __builtin_amdgcn_mfma_f32_16x16x32_bf16(Wf, Af[1][ks], Ha[nt][1], 0, 0, 0);
      }
    }
    // epilogue: h = nt*16 + quad*4 + r (contiguous in r), tok = mt*16 + row
#pragma unroll
    for (int nt = 0; nt < 4; nt++) {
      float4 bb = *(const float4*)&b1[ch * 64 + nt * 16 + quad * 4];
#pragma unroll
      for (int mt = 0; mt < 2; mt++) {
        us4 hv;
        hv[0] = f2us(gelu_fast(Ha[nt][mt][0] + bb.x));
        hv[1] = f2us(gelu_fast(Ha[nt][mt][1] + bb.y));
        hv[2] = f2us(gelu_fast(Ha[nt][mt][2] + bb.z));
        hv[3] = f2us(gelu_fast(Ha[nt][mt][3] + bb.w));
        *(us4*)&Hs[wvb + (mt * 16 + row) * 72 + nt * 16 + quad * 4] = hv;
      }
    }
    __syncthreads();  // phase-lock waves (scheduling aid; Hs is per-wave)
    // GEMM2: O += H[32 tok x 64 h] x W2[64 h x 128 c]
    bf16x8 A2[2][2];
#pragma unroll
    for (int mt = 0; mt < 2; mt++)
#pragma unroll
      for (int ks = 0; ks < 2; ks++)
        A2[mt][ks] = *(const bf16x8*)&Hs[wvb + (mt * 16 + row) * 72 + ks * 32 + quad * 8];
#pragma unroll
    for (int nt = 0; nt < 8; nt++) {
#pragma unroll
      for (int ks = 0; ks < 2; ks++) {
        bf16x8 Bf = *(const bf16x8*)&w2b[(long)(((nt * 16 + ch * 2 + ks) << 6) + lane) * 8];
        Oa[0][nt] = __builtin_amdgcn_mfma_f32_16x16x32_bf16(A2[0][ks], Bf, Oa[0][nt], 0, 0, 0);
        Oa[1][nt] = __builtin_amdgcn_mfma_f32_16x16x32_bf16(A2[1][ks], Bf, Oa[1][nt], 0, 0, 0);
      }
    }
    __syncthreads();
  }
  // final epilogue: +b2, store [c][tok] fp32, accumulate bn2 partials
#pragma unroll
  for (int nt = 0; nt < 8; nt++) {
    int c = nt * 16 + row;
    float bb = b2[c];
    long op = base + (long)c * HWW + wv * 32 + quad * 4;
    float s = 0.f, s2 = 0.f;
#pragma unroll
    for (int mt = 0; mt < 2; mt++) {
      floatx4 vv = Oa[mt][nt];
      vv[0] += bb; vv[1] += bb; vv[2] += bb; vv[3] += bb;
      *(floatx4*)&tmid[op + mt * 16] = vv;
      s += vv[0] + vv[1] + vv[2] + vv[3];
      s2 += vv[0] * vv[0] + vv[1] * vv[1] + vv[2] * vv[2] + vv[3] * vv[3];
    }
    atomicAdd(&ps[c], s);
    atomicAdd(&ps2[c], s2);
  }
  __syncthreads();
  if (tid < 128) {
    atomicAdd(&part2[tid], ps[tid]);
    atomicAdd(&part2[128 + tid], ps2[tid]);
  }
}

// ---------------- Kernel H: bn2 + residual + gelu (stats2b fused) ---------
__global__ __launch_bounds__(256) void k_final(
    const float* __restrict__ x, const float* __restrict__ part2,
    const float* __restrict__ g2, const float* __restrict__ b2n,
    float* __restrict__ out) {
  long e4 = (long)blockIdx.x * 256 + threadIdx.x;
  int c = (int)((e4 >> 12) & 127);
  float mu = part2[c] * (1.f / 65536.f);
  float var = part2[128 + c] * (1.f / 65536.f) - mu * mu;
  float sc = rsqrtf(var + 1e-5f) * g2[c];
  float sh = b2n[c] - mu * sc;
  float4 o = *(float4*)&out[e4 * 4];
  float4 xv = *(const float4*)&x[e4 * 4];
  o.x = gelu_fast(xv.x + o.x * sc + sh);
  o.y = gelu_fast(xv.y + o.y * sc + sh);
  o.z = gelu_fast(xv.z + o.z * sc + sh);
  o.w = gelu_fast(xv.w + o.w * sc + sh);
  *(float4*)&out[e4 * 4] = o;
}

extern "C" void kernel_launch(void* const* d_in, const int* in_sizes, int n_in,
                              void* d_out, int out_size, void* d_ws, size_t ws_size,
                              hipStream_t stream) {
  const float* x        = (const float*)d_in[0];
  const float* offset_w = (const float*)d_in[1];
  const float* offset_b = (const float*)d_in[2];
  const float* deform_w = (const float*)d_in[3];
  const float* dw_w     = (const float*)d_in[4];
  const float* dw_b     = (const float*)d_in[5];
  const float* dw2_w    = (const float*)d_in[6];
  const float* dw2_b    = (const float*)d_in[7];
  const float* bn1_g    = (const float*)d_in[8];
  const float* bn1_b    = (const float*)d_in[9];
  const float* w1       = (const float*)d_in[10];
  const float* b1       = (const float*)d_in[11];
  const float* w2       = (const float*)d_in[12];
  const float* b2       = (const float*)d_in[13];
  const float* bn2_g    = (const float*)d_in[14];
  const float* bn2_b    = (const float*)d_in[15];
  float* out = (float*)d_out;

  float* ws    = (float*)d_ws;
  float* off   = ws;                       // 1,179,648 f
  float* ybuf  = ws + 1179648;             // 8,388,608 f
  unsigned short* w1b = (unsigned short*)(ws + 9568768);  // 65,536 us
  unsigned short* w2b = (unsigned short*)(ws + 9601536);  // 65,536 us
  float* part  = ws + 9634304;             // 1,024 f (bn1 partials)
  float* xt    = ws + 9635328;             // 2,097,152 f
  unsigned short* wob = (unsigned short*)(ws + 11732480); // 9,216 us
  unsigned short* w3b = (unsigned short*)(ws + 11737088); // 9,216 us
  unsigned short* xp  = (unsigned short*)(ws + 11741696); // 4,460,544 us
  unsigned short* xp0 = xp;
  unsigned short* xp1 = xp + (long)4 * PREC * 32;
  float* part2 = ws + 13971968;            // 256 f (atomic bn2 accumulators)
  float* tmid  = out;

  k_prep<<<107, 256, 0, stream>>>(xp, part2, w1, w2, w1b, w2b,
                                  offset_w, dw2_w, wob, w3b);
  k_pack<<<2048, 256, 0, stream>>>(x, xp, xt);
  k_conv3<<<1024, 256, 0, stream>>>(xp0, wob, offset_b, off, xp1, w3b, dw2_b, ybuf);
  k_deform<<<512, 256, 0, stream>>>(xt, off, deform_w, ybuf);
  k_dw7<<<2048, 256, 0, stream>>>(x, dw_w, dw_b, ybuf);
  k_stats1<<<512, 256, 0, stream>>>(ybuf, part);
  k_mlp_mfma<<<512, 256, 0, stream>>>(ybuf, part, bn1_g, bn1_b, w1b, b1, w2b, b2, tmid, part2);
  k_final<<<8192, 256, 0, stream>>>(x, part2, bn2_g, bn2_b, out);
}

// Round 12
// 256.271 us; speedup vs baseline: 1.0598x; 1.0298x over previous
//
#include <hip/hip_runtime.h>
#include <hip/hip_bf16.h>
#include <math.h>

#define BB 4
#define CC 128
#define HH 128
#define WWD 128
#define HWW 16384
#define PREC 17424  // 132*132 padded records per plane

typedef __attribute__((ext_vector_type(8))) short bf16x8;
typedef __attribute__((ext_vector_type(4))) float floatx4;
typedef __attribute__((ext_vector_type(4))) unsigned short us4;
typedef __attribute__((ext_vector_type(8))) unsigned short us8;

// tanh-form gelu: x*sigmoid(x*(1.5957691 + 0.0713548*x^2)).
__device__ __forceinline__ float gelu_fast(float v) {
  float u = v * v;
  float z = v * fmaf(0.0713548163f, u, 1.5957691216f);
  float e = __builtin_amdgcn_exp2f(-1.4426950409f * z);
  return v * __builtin_amdgcn_rcpf(1.0f + e);
}
__device__ __forceinline__ unsigned short f2us(float f) {
  union { float f; unsigned int u; } c; c.f = f;
  unsigned int u = c.u;
  return (unsigned short)((u + 0x7FFFu + ((u >> 16) & 1u)) >> 16);
}

// ---------------- Kernel PR: merged prep (zero borders + wprep + wprep2) --
// blocks 0..33: border-zero + part2-zero; 34..97: w1/w2 swizzle;
// 98..106: conv-weight swizzle. No LDS, no barriers.
__global__ __launch_bounds__(256) void k_prep(
    unsigned short* __restrict__ xp, float* __restrict__ part2,
    const float* __restrict__ w1, const float* __restrict__ w2,
    unsigned short* __restrict__ w1b, unsigned short* __restrict__ w2b,
    const float* __restrict__ offw, const float* __restrict__ dilw,
    unsigned short* __restrict__ wob, unsigned short* __restrict__ w3b) {
  int bid = blockIdx.x;
  if (bid < 34) {
    if (bid == 33) { part2[threadIdx.x] = 0.f; return; }
    int g = bid * 256 + threadIdx.x;
    if (g >= 8320) return;
    int pl = g / 1040;
    int r = g - pl * 1040;
    int yy, xx;
    if (r < 528) {                 // rows 0,1,130,131 in full
      int q = r / 132;
      yy = q < 2 ? q : 126 + q;
      xx = r - q * 132;
    } else {                       // cols 0,1,130,131 for rows 2..129
      int r2 = r - 528;
      yy = 2 + (r2 >> 2);
      int side = r2 & 3;
      xx = side < 2 ? side : 128 + side;
    }
    long rec = (long)pl * PREC + yy * 132 + xx;
    unsigned short* d = &xp[rec * 32];
    us8 z = (us8)0;
    *(us8*)&d[0] = z; *(us8*)&d[8] = z; *(us8*)&d[16] = z; *(us8*)&d[24] = z;
  } else if (bid < 98) {
    int t = (bid - 34) * 256 + threadIdx.x;
    int which = t >> 13;
    int u = t & 8191;
    int lane = u & 63;
    int ntks = u >> 6;
    int col = lane & 15, quad = lane >> 4;
    if (which == 0) {
      int nt = ntks >> 2, ks = ntks & 3;
      int n = nt * 16 + col;
      int k0 = ks * 32 + quad * 8;
      unsigned short* d = w1b + (long)u * 8;
#pragma unroll
      for (int j = 0; j < 8; j++) d[j] = f2us(w1[(long)(k0 + j) * 512 + n]);
    } else {
      int nt = ntks >> 4, ks = ntks & 15;
      int n = nt * 16 + col;
      int k0 = ks * 32 + quad * 8;
      unsigned short* d = w2b + (long)u * 8;
#pragma unroll
      for (int j = 0; j < 8; j++) d[j] = f2us(w2[(long)(k0 + j) * 128 + n]);
    }
  } else {
    int t = (bid - 98) * 256 + threadIdx.x;  // 0..2303
    if (t >= 2304) return;
    int which = t >= 1152;
    int u = t - which * 1152;
    int lane = u & 63, tn = u >> 6;          // tn = tap*2 + nt
    int col = lane & 15, quad = lane >> 4;
    int tap = tn >> 1, nt = tn & 1;
    int n = nt * 16 + col;
    const float* W = which ? dilw : offw;
    int noc = which ? 32 : 18;
    unsigned short* d = (which ? w3b : wob) + (long)(tn * 64 + lane) * 8;
#pragma unroll
    for (int j = 0; j < 8; j++)
      d[j] = (n < noc) ? f2us(W[(long)n * 288 + (quad * 8 + j) * 9 + tap]) : (unsigned short)0;
  }
}

// ---------------- Kernel P: pack padded bf16 planes (+ xt fp32 fused) -----
__global__ __launch_bounds__(256) void k_pack(
    const float* __restrict__ x, unsigned short* __restrict__ xp,
    float* __restrict__ xt) {
  __shared__ float t[64 * 33];
  int bid = blockIdx.x;            // 2048 = which(2) x b(4) x pg(256)
  int tid = threadIdx.x;
  int which = bid >> 10, b = (bid >> 8) & 3, pg = bid & 255;
  int cbase = which ? 96 : 0;
  int c = tid >> 3, g8 = tid & 7;
  const float* xpr = x + ((long)b * CC + cbase + c) * HWW + pg * 64 + g8 * 8;
  float4 v0 = *(const float4*)xpr;
  float4 v1 = *(const float4*)(xpr + 4);
  t[(g8 * 8 + 0) * 33 + c] = v0.x; t[(g8 * 8 + 1) * 33 + c] = v0.y;
  t[(g8 * 8 + 2) * 33 + c] = v0.z; t[(g8 * 8 + 3) * 33 + c] = v0.w;
  t[(g8 * 8 + 4) * 33 + c] = v1.x; t[(g8 * 8 + 5) * 33 + c] = v1.y;
  t[(g8 * 8 + 6) * 33 + c] = v1.z; t[(g8 * 8 + 7) * 33 + c] = v1.w;
  __syncthreads();
  int u = tid >> 2, q = tid & 3;
  int p = pg * 64 + u;
  int yy = p >> 7, xx = p & 127;
  long rec = (long)(which * 4 + b) * PREC + (yy + 2) * 132 + xx + 2;
  us8 o;
  float vv[8];
#pragma unroll
  for (int k = 0; k < 8; k++) {
    vv[k] = t[u * 33 + q * 8 + k];
    o[k] = f2us(vv[k]);
  }
  *(us8*)&xp[rec * 32 + q * 8] = o;
  if (which == 0) {
    float* d = xt + ((long)b * HWW + p) * 32 + q * 8;
    float4 o0, o1;
    o0.x = vv[0]; o0.y = vv[1]; o0.z = vv[2]; o0.w = vv[3];
    o1.x = vv[4]; o1.y = vv[5]; o1.z = vv[6]; o1.w = vv[7];
    *(float4*)d = o0;
    *(float4*)(d + 4) = o1;
  }
}

// ---------------- Kernel CV: merged offset-conv + dilated-conv ------------
__global__ __launch_bounds__(256) void k_conv3(
    const unsigned short* __restrict__ xp0, const unsigned short* __restrict__ wob,
    const float* __restrict__ obias, float* __restrict__ off,
    const unsigned short* __restrict__ xp1, const unsigned short* __restrict__ w3b,
    const float* __restrict__ dbias, float* __restrict__ y) {
  int bid0 = blockIdx.x;
  int tid = threadIdx.x;
  int lane = tid & 63, wv = tid >> 6;
  int row = lane & 15, quad = lane >> 4;
  int xb = wv * 32;
  if (bid0 < 512) {
    int bid = bid0;
    int b = bid >> 7, yy = bid & 127;
    const unsigned short* plane = xp0 + (long)b * PREC * 32;
    floatx4 Oa[2][2];
#pragma unroll
    for (int mt = 0; mt < 2; mt++)
#pragma unroll
      for (int nt = 0; nt < 2; nt++) Oa[mt][nt] = (floatx4)0.f;
#pragma unroll
    for (int t = 0; t < 9; t++) {
      int dy = t / 3 - 1, dx = t % 3 - 1;
      const unsigned short* rp = plane + ((long)(yy + 2 + dy) * 132 + 2 + dx + xb) * 32;
      bf16x8 A0 = *(const bf16x8*)&rp[row * 32 + quad * 8];
      bf16x8 A1 = *(const bf16x8*)&rp[(16 + row) * 32 + quad * 8];
#pragma unroll
      for (int nt = 0; nt < 2; nt++) {
        bf16x8 Bf = *(const bf16x8*)&wob[(long)((t * 2 + nt) * 64 + lane) * 8];
        Oa[0][nt] = __builtin_amdgcn_mfma_f32_16x16x32_bf16(A0, Bf, Oa[0][nt], 0, 0, 0);
        Oa[1][nt] = __builtin_amdgcn_mfma_f32_16x16x32_bf16(A1, Bf, Oa[1][nt], 0, 0, 0);
      }
    }
#pragma unroll
    for (int nt = 0; nt < 2; nt++) {
      int oc = nt * 16 + (lane & 15);
      if (oc < 18) {
        float bb = obias[oc];
#pragma unroll
        for (int mt = 0; mt < 2; mt++) {
          floatx4 v = Oa[mt][nt];
          v[0] += bb; v[1] += bb; v[2] += bb; v[3] += bb;
          long p = (long)(b * 18 + oc) * HWW + yy * 128 + xb + mt * 16 + quad * 4;
          *(floatx4*)&off[p] = v;
        }
      }
    }
  } else {
    int bid = bid0 - 512;
    int b = bid >> 7, yy = bid & 127;
    const unsigned short* plane = xp1 + (long)b * PREC * 32;
    floatx4 Oa[2][2];
#pragma unroll
    for (int mt = 0; mt < 2; mt++)
#pragma unroll
      for (int nt = 0; nt < 2; nt++) Oa[mt][nt] = (floatx4)0.f;
#pragma unroll
    for (int t = 0; t < 9; t++) {
      int dy = (t / 3 - 1) * 2, dx = (t % 3 - 1) * 2;
      const unsigned short* rp = plane + ((long)(yy + 2 + dy) * 132 + 2 + dx + xb) * 32;
      bf16x8 A0 = *(const bf16x8*)&rp[row * 32 + quad * 8];
      bf16x8 A1 = *(const bf16x8*)&rp[(16 + row) * 32 + quad * 8];
#pragma unroll
      for (int nt = 0; nt < 2; nt++) {
        bf16x8 Bf = *(const bf16x8*)&w3b[(long)((t * 2 + nt) * 64 + lane) * 8];
        Oa[0][nt] = __builtin_amdgcn_mfma_f32_16x16x32_bf16(A0, Bf, Oa[0][nt], 0, 0, 0);
        Oa[1][nt] = __builtin_amdgcn_mfma_f32_16x16x32_bf16(A1, Bf, Oa[1][nt], 0, 0, 0);
      }
    }
#pragma unroll
    for (int nt = 0; nt < 2; nt++) {
      int oc = nt * 16 + (lane & 15);
      int cp = 65 + 2 * oc;   // c = 96+oc -> (c%64)*2 + c/64
      float bb = dbias[oc];
#pragma unroll
      for (int mt = 0; mt < 2; mt++) {
        floatx4 v = Oa[mt][nt];
        v[0] += bb; v[1] += bb; v[2] += bb; v[3] += bb;
        long p = ((long)b * CC + cp) * HWW + yy * 128 + xb + mt * 16 + quad * 4;
        *(floatx4*)&y[p] = v;
      }
    }
  }
}

// ---------------- Kernel BD: merged deformable-depthwise + depthwise-7x7 --
// blocks 0..511: deform (16 ch/thread; latency-bound gather chains)
// blocks 512..2559: dw7 (LDS-tiled compute)
// Both depend only on post-conv3 state; writes to ybuf are channel-disjoint
// (deform: even 0..62; dw7: even 64..126 + odd 1..63). Merging removes a
// launch gap and co-schedules dw7's compute waves with deform's stalls —
// the same mechanism as the round-8 conv3 merge (the session's one clean
// rest-side win). SEPARATE named __shared__ arrays per branch (no union —
// the round-9 union-across-branches merge failed correctness).
__global__ __launch_bounds__(256) void k_dfw(
    const float* __restrict__ xt, const float* __restrict__ off,
    const float* __restrict__ dw,
    const float* __restrict__ x, const float* __restrict__ w7,
    const float* __restrict__ b7, float* __restrict__ y) {
  __shared__ float wl_d[144];      // deform branch: [k][16]
  __shared__ float tile[22 * 136]; // dw7 branch
  __shared__ float wl7[49];
  __shared__ float bsh;
  int bid0 = blockIdx.x;
  int tid = threadIdx.x;
  if (bid0 < 512) {
    int g = bid0 * 256 + tid;
    int hf = g >> 16;                // uniform per block
    int pix = g & 65535;
    if (tid < 144) {
      int k = tid >> 4, q = tid & 15;
      wl_d[k * 16 + q] = dw[(hf * 16 + q) * 9 + k];
    }
    __syncthreads();
    int b = pix >> 14, p = pix & 16383;
    int i = p >> 7, j = p & 127;
    float acc[16];
#pragma unroll
    for (int q = 0; q < 16; q++) acc[q] = 0.f;
    const float* offb = off + (long)b * 18 * HWW + p;
    const float* xb = xt + (long)b * HWW * 32 + hf * 16;
    for (int k = 0; k < 9; k++) {
      float dy = offb[(long)(2 * k) * HWW];
      float dx = offb[(long)(2 * k + 1) * HWW];
      float ys = (float)i - 1.f + (float)(k / 3) + dy;
      float xs = (float)j - 1.f + (float)(k % 3) + dx;
      float y0 = floorf(ys), x0 = floorf(xs);
      float fy = ys - y0, fx = xs - x0;
      int iy0 = (int)y0, ix0 = (int)x0;
      int iy1 = iy0 + 1, ix1 = ix0 + 1;
      float wy0 = (1.f - fy) * ((iy0 >= 0 && iy0 <= 127) ? 1.f : 0.f);
      float wy1 = fy * ((iy1 >= 0 && iy1 <= 127) ? 1.f : 0.f);
      float wx0 = (1.f - fx) * ((ix0 >= 0 && ix0 <= 127) ? 1.f : 0.f);
      float wx1 = fx * ((ix1 >= 0 && ix1 <= 127) ? 1.f : 0.f);
      int cy0 = min(max(iy0, 0), 127), cy1 = min(max(iy1, 0), 127);
      int cx0 = min(max(ix0, 0), 127), cx1 = min(max(ix1, 0), 127);
      int ci[4] = {cy0 * 128 + cx0, cy0 * 128 + cx1, cy1 * 128 + cx0, cy1 * 128 + cx1};
      float cw[4] = {wy0 * wx0, wy0 * wx1, wy1 * wx0, wy1 * wx1};
      float v[16];
#pragma unroll
      for (int q = 0; q < 16; q++) v[q] = 0.f;
#pragma unroll
      for (int cn = 0; cn < 4; cn++) {
        const float* cp = xb + (long)ci[cn] * 32;
        float wc = cw[cn];
        float4 p0 = *(const float4*)cp;
        float4 p1 = *(const float4*)(cp + 4);
        float4 p2 = *(const float4*)(cp + 8);
        float4 p3 = *(const float4*)(cp + 12);
        v[0] += wc * p0.x;  v[1] += wc * p0.y;  v[2] += wc * p0.z;  v[3] += wc * p0.w;
        v[4] += wc * p1.x;  v[5] += wc * p1.y;  v[6] += wc * p1.z;  v[7] += wc * p1.w;
        v[8] += wc * p2.x;  v[9] += wc * p2.y;  v[10] += wc * p2.z; v[11] += wc * p2.w;
        v[12] += wc * p3.x; v[13] += wc * p3.y; v[14] += wc * p3.z; v[15] += wc * p3.w;
      }
      const float* wr = &wl_d[k * 16];
#pragma unroll
      for (int q = 0; q < 16; q++) acc[q] += wr[q] * v[q];
    }
#pragma unroll
    for (int q = 0; q < 16; q++) {
      int cp = 2 * (hf * 16 + q);
      y[((long)b * CC + cp) * HWW + p] = acc[q];
    }
  } else {
    int bid = bid0 - 512;
    int b = bid >> 9, m = (bid >> 3) & 63, strip = bid & 7;
    int r0 = strip * 16;
    const float* xp = x + ((long)b * CC + 32 + m) * HWW;
    for (int idx = tid; idx < 2948; idx += 256) {
      int rr = idx / 134;
      int cc = idx - rr * 134 - 3;
      int gy = r0 - 3 + rr;
      float v = 0.f;
      if ((unsigned)gy < 128u && (unsigned)cc < 128u) v = xp[gy * 128 + cc];
      tile[rr * 136 + cc + 3] = v;
    }
    if (tid < 49) wl7[tid] = w7[m * 49 + tid];
    if (tid == 64) bsh = b7[m];
    __syncthreads();
    int j = tid & 127, s = tid >> 7;
    float acc[8];
#pragma unroll
    for (int o = 0; o < 8; o++) acc[o] = bsh;
#pragma unroll
    for (int kx = 0; kx < 7; kx++) {
#pragma unroll
      for (int rr = 0; rr < 14; rr++) {
        float v = tile[(s * 8 + rr) * 136 + j + kx];
        int olo = rr - 6 > 0 ? rr - 6 : 0;
        int ohi = rr < 7 ? rr : 7;
#pragma unroll
        for (int o = 0; o < 8; o++) {
          if (o >= olo && o <= ohi) acc[o] += v * wl7[(rr - o) * 7 + kx];
        }
      }
    }
    int c = 32 + m;
    int cp = (c & 63) * 2 + (c >> 6);
    float* yp = y + ((long)b * CC + cp) * HWW;
#pragma unroll
    for (int o = 0; o < 8; o++) {
      yp[(r0 + s * 8 + o) * 128 + j] = acc[o];
    }
  }
}

// ---------------- stats (bn1): stage 1 only (stage 2 fused into k_mlp) ----
__global__ __launch_bounds__(256) void k_stats1(
    const float* __restrict__ buf, float* __restrict__ part) {
  __shared__ float sh[256], sh2[256];
  int c = blockIdx.x >> 2, b = blockIdx.x & 3;
  int tid = threadIdx.x;
  const float* p = buf + ((long)b * CC + c) * HWW;
  float s = 0.f, s2 = 0.f;
  for (int it = 0; it < 16; it++) {
    float4 v = *(const float4*)(p + (it * 256 + tid) * 4);
    s += v.x + v.y + v.z + v.w;
    s2 += v.x * v.x + v.y * v.y + v.z * v.z + v.w * v.w;
  }
  sh[tid] = s; sh2[tid] = s2;
  __syncthreads();
  for (int o = 128; o > 0; o >>= 1) {
    if (tid < o) { sh[tid] += sh[tid + o]; sh2[tid] += sh2[tid + o]; }
    __syncthreads();
  }
  if (tid == 0) {
    part[blockIdx.x * 2] = sh[0];
    part[blockIdx.x * 2 + 1] = sh2[0];
  }
}

// ---------------- Kernel F: BN1 + MLP via bf16 MFMA (H^T + fast gelu) -----
// GEMM1 computes H^T so gelu'd writes to Hs[tok][h] are contiguous (us4).
// Per-chunk barriers: measured removing them costs ~12 µs (wave phase
// drift). bn1 stage-2 computed per-block in the preamble; bn2 partials in
// epilogue. NOTE: 64-token tiles, register H-handoff, and split-streaming
// MLP all measured SLOWER (83/96/305/328 µs vs 68-70). This exact structure
// is the empirical optimum; schedule-fragile — do not perturb.
__global__ __launch_bounds__(256, 2) void k_mlp_mfma(
    const float* __restrict__ y, const float* __restrict__ part,
    const float* __restrict__ g1, const float* __restrict__ b1n,
    const unsigned short* __restrict__ w1b, const float* __restrict__ b1,
    const unsigned short* __restrict__ w2b, const float* __restrict__ b2,
    float* __restrict__ tmid, float* __restrict__ part2) {
  __shared__ unsigned short At[128 * 136];
  __shared__ unsigned short Hs[4 * 32 * 72];
  __shared__ float scs[128], shs[128];
  __shared__ float ps[128], ps2[128];
  int tid = threadIdx.x;
  int lane = tid & 63, wv = tid >> 6;
  int row = lane & 15, quad = lane >> 4;
  int n0 = blockIdx.x * 128;
  int b = n0 >> 14;
  long base = (long)b * CC * HWW + (n0 & 16383);
  if (tid < 128) {
    float s = 0.f, s2 = 0.f;
#pragma unroll
    for (int bq = 0; bq < 4; bq++) {
      s  += part[(tid * 4 + bq) * 2];
      s2 += part[(tid * 4 + bq) * 2 + 1];
    }
    float mu = s * (1.f / 65536.f);
    float var = s2 * (1.f / 65536.f) - mu * mu;
    float sc = rsqrtf(var + 1e-5f) * g1[tid];
    scs[tid] = sc;
    shs[tid] = b1n[tid] - mu * sc;
    ps[tid] = 0.f; ps2[tid] = 0.f;
  }
  __syncthreads();
  for (int it = 0; it < 16; it++) {
    int u = it * 256 + tid;
    int tok = u & 127, cg = u >> 7;
    us4 wvv;
#pragma unroll
    for (int r = 0; r < 4; r++) {
      int c = cg * 4 + r;
      float v = y[base + (long)c * HWW + tok];
      wvv[r] = f2us(v * scs[c] + shs[c]);
    }
    *(us4*)&At[tok * 136 + cg * 4] = wvv;
  }
  __syncthreads();
  bf16x8 Af[2][4];
#pragma unroll
  for (int mt = 0; mt < 2; mt++)
#pragma unroll
    for (int ks = 0; ks < 4; ks++)
      Af[mt][ks] = *(const bf16x8*)&At[(wv * 32 + mt * 16 + row) * 136 + ks * 32 + quad * 8];

  floatx4 Oa[2][8];
#pragma unroll
  for (int mt = 0; mt < 2; mt++)
#pragma unroll
    for (int nt = 0; nt < 8; nt++) Oa[mt][nt] = (floatx4)0.f;

  const int wvb = wv * 32 * 72;
  for (int ch = 0; ch < 8; ch++) {
    // GEMM1 (H^T): M = 64 hidden (4 tiles), N = 32 tokens (2 tiles)
    floatx4 Ha[4][2];
#pragma unroll
    for (int nt = 0; nt < 4; nt++)
#pragma unroll
      for (int mt = 0; mt < 2; mt++) Ha[nt][mt] = (floatx4)0.f;
#pragma unroll
    for (int nt = 0; nt < 4; nt++) {
      int ht = ch * 4 + nt;
#pragma unroll
      for (int ks = 0; ks < 4; ks++) {
        bf16x8 Wf = *(const bf16x8*)&w1b[(long)(((ht * 4 + ks) << 6) + lane) * 8];
        Ha[nt][0] = __builtin_amdgcn_mfma_f32_16x16x32_bf16(Wf, Af[0][ks], Ha[nt][0], 0, 0, 0);
        Ha[nt][1] = __builtin_amdgcn_mfma_f32_16x16x32_bf16(Wf, Af[1][ks], Ha[nt][1], 0, 0, 0);
      }
    }
    // epilogue: h = nt*16 + quad*4 + r (contiguous in r), tok = mt*16 + row
#pragma unroll
    for (int nt = 0; nt < 4; nt++) {
      float4 bb = *(const float4*)&b1[ch * 64 + nt * 16 + quad * 4];
#pragma unroll
      for (int mt = 0; mt < 2; mt++) {
        us4 hv;
        hv[0] = f2us(gelu_fast(Ha[nt][mt][0] + bb.x));
        hv[1] = f2us(gelu_fast(Ha[nt][mt][1] + bb.y));
        hv[2] = f2us(gelu_fast(Ha[nt][mt][2] + bb.z));
        hv[3] = f2us(gelu_fast(Ha[nt][mt][3] + bb.w));
        *(us4*)&Hs[wvb + (mt * 16 + row) * 72 + nt * 16 + quad * 4] = hv;
      }
    }
    __syncthreads();  // phase-lock waves (scheduling aid; Hs is per-wave)
    // GEMM2: O += H[32 tok x 64 h] x W2[64 h x 128 c]
    bf16x8 A2[2][2];
#pragma unroll
    for (int mt = 0; mt < 2; mt++)
#pragma unroll
      for (int ks = 0; ks < 2; ks++)
        A2[mt][ks] = *(const bf16x8*)&Hs[wvb + (mt * 16 + row) * 72 + ks * 32 + quad * 8];
#pragma unroll
    for (int nt = 0; nt < 8; nt++) {
#pragma unroll
      for (int ks = 0; ks < 2; ks++) {
        bf16x8 Bf = *(const bf16x8*)&w2b[(long)(((nt * 16 + ch * 2 + ks) << 6) + lane) * 8];
        Oa[0][nt] = __builtin_amdgcn_mfma_f32_16x16x32_bf16(A2[0][ks], Bf, Oa[0][nt], 0, 0, 0);
        Oa[1][nt] = __builtin_amdgcn_mfma_f32_16x16x32_bf16(A2[1][ks], Bf, Oa[1][nt], 0, 0, 0);
      }
    }
    __syncthreads();
  }
  // final epilogue: +b2, store [c][tok] fp32, accumulate bn2 partials
#pragma unroll
  for (int nt = 0; nt < 8; nt++) {
    int c = nt * 16 + row;
    float bb = b2[c];
    long op = base + (long)c * HWW + wv * 32 + quad * 4;
    float s = 0.f, s2 = 0.f;
#pragma unroll
    for (int mt = 0; mt < 2; mt++) {
      floatx4 vv = Oa[mt][nt];
      vv[0] += bb; vv[1] += bb; vv[2] += bb; vv[3] += bb;
      *(floatx4*)&tmid[op + mt * 16] = vv;
      s += vv[0] + vv[1] + vv[2] + vv[3];
      s2 += vv[0] * vv[0] + vv[1] * vv[1] + vv[2] * vv[2] + vv[3] * vv[3];
    }
    atomicAdd(&ps[c], s);
    atomicAdd(&ps2[c], s2);
  }
  __syncthreads();
  if (tid < 128) {
    atomicAdd(&part2[tid], ps[tid]);
    atomicAdd(&part2[128 + tid], ps2[tid]);
  }
}

// ---------------- Kernel H: bn2 + residual + gelu (stats2b fused) ---------
__global__ __launch_bounds__(256) void k_final(
    const float* __restrict__ x, const float* __restrict__ part2,
    const float* __restrict__ g2, const float* __restrict__ b2n,
    float* __restrict__ out) {
  long e4 = (long)blockIdx.x * 256 + threadIdx.x;
  int c = (int)((e4 >> 12) & 127);
  float mu = part2[c] * (1.f / 65536.f);
  float var = part2[128 + c] * (1.f / 65536.f) - mu * mu;
  float sc = rsqrtf(var + 1e-5f) * g2[c];
  float sh = b2n[c] - mu * sc;
  float4 o = *(float4*)&out[e4 * 4];
  float4 xv = *(const float4*)&x[e4 * 4];
  o.x = gelu_fast(xv.x + o.x * sc + sh);
  o.y = gelu_fast(xv.y + o.y * sc + sh);
  o.z = gelu_fast(xv.z + o.z * sc + sh);
  o.w = gelu_fast(xv.w + o.w * sc + sh);
  *(float4*)&out[e4 * 4] = o;
}

extern "C" void kernel_launch(void* const* d_in, const int* in_sizes, int n_in,
                              void* d_out, int out_size, void* d_ws, size_t ws_size,
                              hipStream_t stream) {
  const float* x        = (const float*)d_in[0];
  const float* offset_w = (const float*)d_in[1];
  const float* offset_b = (const float*)d_in[2];
  const float* deform_w = (const float*)d_in[3];
  const float* dw_w     = (const float*)d_in[4];
  const float* dw_b     = (const float*)d_in[5];
  const float* dw2_w    = (const float*)d_in[6];
  const float* dw2_b    = (const float*)d_in[7];
  const float* bn1_g    = (const float*)d_in[8];
  const float* bn1_b    = (const float*)d_in[9];
  const float* w1       = (const float*)d_in[10];
  const float* b1       = (const float*)d_in[11];
  const float* w2       = (const float*)d_in[12];
  const float* b2       = (const float*)d_in[13];
  const float* bn2_g    = (const float*)d_in[14];
  const float* bn2_b    = (const float*)d_in[15];
  float* out = (float*)d_out;

  float* ws    = (float*)d_ws;
  float* off   = ws;                       // 1,179,648 f
  float* ybuf  = ws + 1179648;             // 8,388,608 f
  unsigned short* w1b = (unsigned short*)(ws + 9568768);  // 65,536 us
  unsigned short* w2b = (unsigned short*)(ws + 9601536);  // 65,536 us
  float* part  = ws + 9634304;             // 1,024 f (bn1 partials)
  float* xt    = ws + 9635328;             // 2,097,152 f
  unsigned short* wob = (unsigned short*)(ws + 11732480); // 9,216 us
  unsigned short* w3b = (unsigned short*)(ws + 11737088); // 9,216 us
  unsigned short* xp  = (unsigned short*)(ws + 11741696); // 4,460,544 us
  unsigned short* xp0 = xp;
  unsigned short* xp1 = xp + (long)4 * PREC * 32;
  float* part2 = ws + 13971968;            // 256 f (atomic bn2 accumulators)
  float* tmid  = out;

  k_prep<<<107, 256, 0, stream>>>(xp, part2, w1, w2, w1b, w2b,
                                  offset_w, dw2_w, wob, w3b);
  k_pack<<<2048, 256, 0, stream>>>(x, xp, xt);
  k_conv3<<<1024, 256, 0, stream>>>(xp0, wob, offset_b, off, xp1, w3b, dw2_b, ybuf);
  k_dfw<<<2560, 256, 0, stream>>>(xt, off, deform_w, x, dw_w, dw_b, ybuf);
  k_stats1<<<512, 256, 0, stream>>>(ybuf, part);
  k_mlp_mfma<<<512, 256, 0, stream>>>(ybuf, part, bn1_g, bn1_b, w1b, b1, w2b, b2, tmid, part2);
  k_final<<<8192, 256, 0, stream>>>(x, part2, bn2_g, bn2_b, out);
}

// Round 14
// 253.933 us; speedup vs baseline: 1.0696x; 1.0092x over previous
//
#include <hip/hip_runtime.h>
#include <hip/hip_bf16.h>
#include <math.h>

#define BB 4
#define CC 128
#define HH 128
#define WWD 128
#define HWW 16384
#define PREC 17424  // 132*132 padded records per plane

typedef __attribute__((ext_vector_type(8))) short bf16x8;
typedef __attribute__((ext_vector_type(4))) float floatx4;
typedef __attribute__((ext_vector_type(4))) unsigned short us4;
typedef __attribute__((ext_vector_type(8))) unsigned short us8;

// tanh-form gelu: x*sigmoid(x*(1.5957691 + 0.0713548*x^2)).
__device__ __forceinline__ float gelu_fast(float v) {
  float u = v * v;
  float z = v * fmaf(0.0713548163f, u, 1.5957691216f);
  float e = __builtin_amdgcn_exp2f(-1.4426950409f * z);
  return v * __builtin_amdgcn_rcpf(1.0f + e);
}
__device__ __forceinline__ unsigned short f2us(float f) {
  union { float f; unsigned int u; } c; c.f = f;
  unsigned int u = c.u;
  return (unsigned short)((u + 0x7FFFu + ((u >> 16) & 1u)) >> 16);
}

// ---------------- Kernel PR: merged prep (zero borders + wprep + wprep2) --
// blocks 0..33: border-zero + part2-zero; 34..97: w1/w2 swizzle;
// 98..106: conv-weight swizzle. No LDS, no barriers.
// DO NOT fold k_pack in here: measured correctness failure twice
// (rounds 9 and 13, absmax ~2.4-2.6) despite clean inspection.
__global__ __launch_bounds__(256) void k_prep(
    unsigned short* __restrict__ xp, float* __restrict__ part2,
    const float* __restrict__ w1, const float* __restrict__ w2,
    unsigned short* __restrict__ w1b, unsigned short* __restrict__ w2b,
    const float* __restrict__ offw, const float* __restrict__ dilw,
    unsigned short* __restrict__ wob, unsigned short* __restrict__ w3b) {
  int bid = blockIdx.x;
  if (bid < 34) {
    if (bid == 33) { part2[threadIdx.x] = 0.f; return; }
    int g = bid * 256 + threadIdx.x;
    if (g >= 8320) return;
    int pl = g / 1040;
    int r = g - pl * 1040;
    int yy, xx;
    if (r < 528) {                 // rows 0,1,130,131 in full
      int q = r / 132;
      yy = q < 2 ? q : 126 + q;
      xx = r - q * 132;
    } else {                       // cols 0,1,130,131 for rows 2..129
      int r2 = r - 528;
      yy = 2 + (r2 >> 2);
      int side = r2 & 3;
      xx = side < 2 ? side : 128 + side;
    }
    long rec = (long)pl * PREC + yy * 132 + xx;
    unsigned short* d = &xp[rec * 32];
    us8 z = (us8)0;
    *(us8*)&d[0] = z; *(us8*)&d[8] = z; *(us8*)&d[16] = z; *(us8*)&d[24] = z;
  } else if (bid < 98) {
    int t = (bid - 34) * 256 + threadIdx.x;
    int which = t >> 13;
    int u = t & 8191;
    int lane = u & 63;
    int ntks = u >> 6;
    int col = lane & 15, quad = lane >> 4;
    if (which == 0) {
      int nt = ntks >> 2, ks = ntks & 3;
      int n = nt * 16 + col;
      int k0 = ks * 32 + quad * 8;
      unsigned short* d = w1b + (long)u * 8;
#pragma unroll
      for (int j = 0; j < 8; j++) d[j] = f2us(w1[(long)(k0 + j) * 512 + n]);
    } else {
      int nt = ntks >> 4, ks = ntks & 15;
      int n = nt * 16 + col;
      int k0 = ks * 32 + quad * 8;
      unsigned short* d = w2b + (long)u * 8;
#pragma unroll
      for (int j = 0; j < 8; j++) d[j] = f2us(w2[(long)(k0 + j) * 128 + n]);
    }
  } else {
    int t = (bid - 98) * 256 + threadIdx.x;  // 0..2303
    if (t >= 2304) return;
    int which = t >= 1152;
    int u = t - which * 1152;
    int lane = u & 63, tn = u >> 6;          // tn = tap*2 + nt
    int col = lane & 15, quad = lane >> 4;
    int tap = tn >> 1, nt = tn & 1;
    int n = nt * 16 + col;
    const float* W = which ? dilw : offw;
    int noc = which ? 32 : 18;
    unsigned short* d = (which ? w3b : wob) + (long)(tn * 64 + lane) * 8;
#pragma unroll
    for (int j = 0; j < 8; j++)
      d[j] = (n < noc) ? f2us(W[(long)n * 288 + (quad * 8 + j) * 9 + tap]) : (unsigned short)0;
  }
}

// ---------------- Kernel P: pack padded bf16 planes (+ xt fp32 fused) -----
// Standalone: merging this kernel into k_prep failed correctness twice.
__global__ __launch_bounds__(256) void k_pack(
    const float* __restrict__ x, unsigned short* __restrict__ xp,
    float* __restrict__ xt) {
  __shared__ float t[64 * 33];
  int bid = blockIdx.x;            // 2048 = which(2) x b(4) x pg(256)
  int tid = threadIdx.x;
  int which = bid >> 10, b = (bid >> 8) & 3, pg = bid & 255;
  int cbase = which ? 96 : 0;
  int c = tid >> 3, g8 = tid & 7;
  const float* xpr = x + ((long)b * CC + cbase + c) * HWW + pg * 64 + g8 * 8;
  float4 v0 = *(const float4*)xpr;
  float4 v1 = *(const float4*)(xpr + 4);
  t[(g8 * 8 + 0) * 33 + c] = v0.x; t[(g8 * 8 + 1) * 33 + c] = v0.y;
  t[(g8 * 8 + 2) * 33 + c] = v0.z; t[(g8 * 8 + 3) * 33 + c] = v0.w;
  t[(g8 * 8 + 4) * 33 + c] = v1.x; t[(g8 * 8 + 5) * 33 + c] = v1.y;
  t[(g8 * 8 + 6) * 33 + c] = v1.z; t[(g8 * 8 + 7) * 33 + c] = v1.w;
  __syncthreads();
  int u = tid >> 2, q = tid & 3;
  int p = pg * 64 + u;
  int yy = p >> 7, xx = p & 127;
  long rec = (long)(which * 4 + b) * PREC + (yy + 2) * 132 + xx + 2;
  us8 o;
  float vv[8];
#pragma unroll
  for (int k = 0; k < 8; k++) {
    vv[k] = t[u * 33 + q * 8 + k];
    o[k] = f2us(vv[k]);
  }
  *(us8*)&xp[rec * 32 + q * 8] = o;
  if (which == 0) {
    float* d = xt + ((long)b * HWW + p) * 32 + q * 8;
    float4 o0, o1;
    o0.x = vv[0]; o0.y = vv[1]; o0.z = vv[2]; o0.w = vv[3];
    o1.x = vv[4]; o1.y = vv[5]; o1.z = vv[6]; o1.w = vv[7];
    *(float4*)d = o0;
    *(float4*)(d + 4) = o1;
  }
}

// ---------------- Kernel CV: merged offset-conv + dilated-conv ------------
__global__ __launch_bounds__(256) void k_conv3(
    const unsigned short* __restrict__ xp0, const unsigned short* __restrict__ wob,
    const float* __restrict__ obias, float* __restrict__ off,
    const unsigned short* __restrict__ xp1, const unsigned short* __restrict__ w3b,
    const float* __restrict__ dbias, float* __restrict__ y) {
  int bid0 = blockIdx.x;
  int tid = threadIdx.x;
  int lane = tid & 63, wv = tid >> 6;
  int row = lane & 15, quad = lane >> 4;
  int xb = wv * 32;
  if (bid0 < 512) {
    int bid = bid0;
    int b = bid >> 7, yy = bid & 127;
    const unsigned short* plane = xp0 + (long)b * PREC * 32;
    floatx4 Oa[2][2];
#pragma unroll
    for (int mt = 0; mt < 2; mt++)
#pragma unroll
      for (int nt = 0; nt < 2; nt++) Oa[mt][nt] = (floatx4)0.f;
#pragma unroll
    for (int t = 0; t < 9; t++) {
      int dy = t / 3 - 1, dx = t % 3 - 1;
      const unsigned short* rp = plane + ((long)(yy + 2 + dy) * 132 + 2 + dx + xb) * 32;
      bf16x8 A0 = *(const bf16x8*)&rp[row * 32 + quad * 8];
      bf16x8 A1 = *(const bf16x8*)&rp[(16 + row) * 32 + quad * 8];
#pragma unroll
      for (int nt = 0; nt < 2; nt++) {
        bf16x8 Bf = *(const bf16x8*)&wob[(long)((t * 2 + nt) * 64 + lane) * 8];
        Oa[0][nt] = __builtin_amdgcn_mfma_f32_16x16x32_bf16(A0, Bf, Oa[0][nt], 0, 0, 0);
        Oa[1][nt] = __builtin_amdgcn_mfma_f32_16x16x32_bf16(A1, Bf, Oa[1][nt], 0, 0, 0);
      }
    }
#pragma unroll
    for (int nt = 0; nt < 2; nt++) {
      int oc = nt * 16 + (lane & 15);
      if (oc < 18) {
        float bb = obias[oc];
#pragma unroll
        for (int mt = 0; mt < 2; mt++) {
          floatx4 v = Oa[mt][nt];
          v[0] += bb; v[1] += bb; v[2] += bb; v[3] += bb;
          long p = (long)(b * 18 + oc) * HWW + yy * 128 + xb + mt * 16 + quad * 4;
          *(floatx4*)&off[p] = v;
        }
      }
    }
  } else {
    int bid = bid0 - 512;
    int b = bid >> 7, yy = bid & 127;
    const unsigned short* plane = xp1 + (long)b * PREC * 32;
    floatx4 Oa[2][2];
#pragma unroll
    for (int mt = 0; mt < 2; mt++)
#pragma unroll
      for (int nt = 0; nt < 2; nt++) Oa[mt][nt] = (floatx4)0.f;
#pragma unroll
    for (int t = 0; t < 9; t++) {
      int dy = (t / 3 - 1) * 2, dx = (t % 3 - 1) * 2;
      const unsigned short* rp = plane + ((long)(yy + 2 + dy) * 132 + 2 + dx + xb) * 32;
      bf16x8 A0 = *(const bf16x8*)&rp[row * 32 + quad * 8];
      bf16x8 A1 = *(const bf16x8*)&rp[(16 + row) * 32 + quad * 8];
#pragma unroll
      for (int nt = 0; nt < 2; nt++) {
        bf16x8 Bf = *(const bf16x8*)&w3b[(long)((t * 2 + nt) * 64 + lane) * 8];
        Oa[0][nt] = __builtin_amdgcn_mfma_f32_16x16x32_bf16(A0, Bf, Oa[0][nt], 0, 0, 0);
        Oa[1][nt] = __builtin_amdgcn_mfma_f32_16x16x32_bf16(A1, Bf, Oa[1][nt], 0, 0, 0);
      }
    }
#pragma unroll
    for (int nt = 0; nt < 2; nt++) {
      int oc = nt * 16 + (lane & 15);
      int cp = 65 + 2 * oc;   // c = 96+oc -> (c%64)*2 + c/64
      float bb = dbias[oc];
#pragma unroll
      for (int mt = 0; mt < 2; mt++) {
        floatx4 v = Oa[mt][nt];
        v[0] += bb; v[1] += bb; v[2] += bb; v[3] += bb;
        long p = ((long)b * CC + cp) * HWW + yy * 128 + xb + mt * 16 + quad * 4;
        *(floatx4*)&y[p] = v;
      }
    }
  }
}

// ---------------- Kernel BD: merged deformable-depthwise + depthwise-7x7 --
// blocks 0..511: deform (16 ch/thread); 512..2559: dw7. Channel-disjoint
// ybuf writes; separate named __shared__ arrays per branch.
__global__ __launch_bounds__(256) void k_dfw(
    const float* __restrict__ xt, const float* __restrict__ off,
    const float* __restrict__ dw,
    const float* __restrict__ x, const float* __restrict__ w7,
    const float* __restrict__ b7, float* __restrict__ y) {
  __shared__ float wl_d[144];      // deform branch: [k][16]
  __shared__ float tile[22 * 136]; // dw7 branch
  __shared__ float wl7[49];
  __shared__ float bsh;
  int bid0 = blockIdx.x;
  int tid = threadIdx.x;
  if (bid0 < 512) {
    int g = bid0 * 256 + tid;
    int hf = g >> 16;                // uniform per block
    int pix = g & 65535;
    if (tid < 144) {
      int k = tid >> 4, q = tid & 15;
      wl_d[k * 16 + q] = dw[(hf * 16 + q) * 9 + k];
    }
    __syncthreads();
    int b = pix >> 14, p = pix & 16383;
    int i = p >> 7, j = p & 127;
    float acc[16];
#pragma unroll
    for (int q = 0; q < 16; q++) acc[q] = 0.f;
    const float* offb = off + (long)b * 18 * HWW + p;
    const float* xb = xt + (long)b * HWW * 32 + hf * 16;
    for (int k = 0; k < 9; k++) {
      float dy = offb[(long)(2 * k) * HWW];
      float dx = offb[(long)(2 * k + 1) * HWW];
      float ys = (float)i - 1.f + (float)(k / 3) + dy;
      float xs = (float)j - 1.f + (float)(k % 3) + dx;
      float y0 = floorf(ys), x0 = floorf(xs);
      float fy = ys - y0, fx = xs - x0;
      int iy0 = (int)y0, ix0 = (int)x0;
      int iy1 = iy0 + 1, ix1 = ix0 + 1;
      float wy0 = (1.f - fy) * ((iy0 >= 0 && iy0 <= 127) ? 1.f : 0.f);
      float wy1 = fy * ((iy1 >= 0 && iy1 <= 127) ? 1.f : 0.f);
      float wx0 = (1.f - fx) * ((ix0 >= 0 && ix0 <= 127) ? 1.f : 0.f);
      float wx1 = fx * ((ix1 >= 0 && ix1 <= 127) ? 1.f : 0.f);
      int cy0 = min(max(iy0, 0), 127), cy1 = min(max(iy1, 0), 127);
      int cx0 = min(max(ix0, 0), 127), cx1 = min(max(ix1, 0), 127);
      int ci[4] = {cy0 * 128 + cx0, cy0 * 128 + cx1, cy1 * 128 + cx0, cy1 * 128 + cx1};
      float cw[4] = {wy0 * wx0, wy0 * wx1, wy1 * wx0, wy1 * wx1};
      float v[16];
#pragma unroll
      for (int q = 0; q < 16; q++) v[q] = 0.f;
#pragma unroll
      for (int cn = 0; cn < 4; cn++) {
        const float* cp = xb + (long)ci[cn] * 32;
        float wc = cw[cn];
        float4 p0 = *(const float4*)cp;
        float4 p1 = *(const float4*)(cp + 4);
        float4 p2 = *(const float4*)(cp + 8);
        float4 p3 = *(const float4*)(cp + 12);
        v[0] += wc * p0.x;  v[1] += wc * p0.y;  v[2] += wc * p0.z;  v[3] += wc * p0.w;
        v[4] += wc * p1.x;  v[5] += wc * p1.y;  v[6] += wc * p1.z;  v[7] += wc * p1.w;
        v[8] += wc * p2.x;  v[9] += wc * p2.y;  v[10] += wc * p2.z; v[11] += wc * p2.w;
        v[12] += wc * p3.x; v[13] += wc * p3.y; v[14] += wc * p3.z; v[15] += wc * p3.w;
      }
      const float* wr = &wl_d[k * 16];
#pragma unroll
      for (int q = 0; q < 16; q++) acc[q] += wr[q] * v[q];
    }
#pragma unroll
    for (int q = 0; q < 16; q++) {
      int cp = 2 * (hf * 16 + q);
      y[((long)b * CC + cp) * HWW + p] = acc[q];
    }
  } else {
    int bid = bid0 - 512;
    int b = bid >> 9, m = (bid >> 3) & 63, strip = bid & 7;
    int r0 = strip * 16;
    const float* xp = x + ((long)b * CC + 32 + m) * HWW;
    for (int idx = tid; idx < 2948; idx += 256) {
      int rr = idx / 134;
      int cc = idx - rr * 134 - 3;
      int gy = r0 - 3 + rr;
      float v = 0.f;
      if ((unsigned)gy < 128u && (unsigned)cc < 128u) v = xp[gy * 128 + cc];
      tile[rr * 136 + cc + 3] = v;
    }
    if (tid < 49) wl7[tid] = w7[m * 49 + tid];
    if (tid == 64) bsh = b7[m];
    __syncthreads();
    int j = tid & 127, s = tid >> 7;
    float acc[8];
#pragma unroll
    for (int o = 0; o < 8; o++) acc[o] = bsh;
#pragma unroll
    for (int kx = 0; kx < 7; kx++) {
#pragma unroll
      for (int rr = 0; rr < 14; rr++) {
        float v = tile[(s * 8 + rr) * 136 + j + kx];
        int olo = rr - 6 > 0 ? rr - 6 : 0;
        int ohi = rr < 7 ? rr : 7;
#pragma unroll
        for (int o = 0; o < 8; o++) {
          if (o >= olo && o <= ohi) acc[o] += v * wl7[(rr - o) * 7 + kx];
        }
      }
    }
    int c = 32 + m;
    int cp = (c & 63) * 2 + (c >> 6);
    float* yp = y + ((long)b * CC + cp) * HWW;
#pragma unroll
    for (int o = 0; o < 8; o++) {
      yp[(r0 + s * 8 + o) * 128 + j] = acc[o];
    }
  }
}

// ---------------- stats (bn1): stage 1 only (stage 2 fused into k_mlp) ----
__global__ __launch_bounds__(256) void k_stats1(
    const float* __restrict__ buf, float* __restrict__ part) {
  __shared__ float sh[256], sh2[256];
  int c = blockIdx.x >> 2, b = blockIdx.x & 3;
  int tid = threadIdx.x;
  const float* p = buf + ((long)b * CC + c) * HWW;
  float s = 0.f, s2 = 0.f;
  for (int it = 0; it < 16; it++) {
    float4 v = *(const float4*)(p + (it * 256 + tid) * 4);
    s += v.x + v.y + v.z + v.w;
    s2 += v.x * v.x + v.y * v.y + v.z * v.z + v.w * v.w;
  }
  sh[tid] = s; sh2[tid] = s2;
  __syncthreads();
  for (int o = 128; o > 0; o >>= 1) {
    if (tid < o) { sh[tid] += sh[tid + o]; sh2[tid] += sh2[tid + o]; }
    __syncthreads();
  }
  if (tid == 0) {
    part[blockIdx.x * 2] = sh[0];
    part[blockIdx.x * 2 + 1] = sh2[0];
  }
}

// ---------------- Kernel F: BN1 + MLP via bf16 MFMA (H^T + fast gelu) -----
// Schedule-fragile empirical optimum — do not perturb (5 restructures all
// measured slower: 83/96/305/328 µs vs 68-70).
__global__ __launch_bounds__(256, 2) void k_mlp_mfma(
    const float* __restrict__ y, const float* __restrict__ part,
    const float* __restrict__ g1, const float* __restrict__ b1n,
    const unsigned short* __restrict__ w1b, const float* __restrict__ b1,
    const unsigned short* __restrict__ w2b, const float* __restrict__ b2,
    float* __restrict__ tmid, float* __restrict__ part2) {
  __shared__ unsigned short At[128 * 136];
  __shared__ unsigned short Hs[4 * 32 * 72];
  __shared__ float scs[128], shs[128];
  __shared__ float ps[128], ps2[128];
  int tid = threadIdx.x;
  int lane = tid & 63, wv = tid >> 6;
  int row = lane & 15, quad = lane >> 4;
  int n0 = blockIdx.x * 128;
  int b = n0 >> 14;
  long base = (long)b * CC * HWW + (n0 & 16383);
  if (tid < 128) {
    float s = 0.f, s2 = 0.f;
#pragma unroll
    for (int bq = 0; bq < 4; bq++) {
      s  += part[(tid * 4 + bq) * 2];
      s2 += part[(tid * 4 + bq) * 2 + 1];
    }
    float mu = s * (1.f / 65536.f);
    float var = s2 * (1.f / 65536.f) - mu * mu;
    float sc = rsqrtf(var + 1e-5f) * g1[tid];
    scs[tid] = sc;
    shs[tid] = b1n[tid] - mu * sc;
    ps[tid] = 0.f; ps2[tid] = 0.f;
  }
  __syncthreads();
  for (int it = 0; it < 16; it++) {
    int u = it * 256 + tid;
    int tok = u & 127, cg = u >> 7;
    us4 wvv;
#pragma unroll
    for (int r = 0; r < 4; r++) {
      int c = cg * 4 + r;
      float v = y[base + (long)c * HWW + tok];
      wvv[r] = f2us(v * scs[c] + shs[c]);
    }
    *(us4*)&At[tok * 136 + cg * 4] = wvv;
  }
  __syncthreads();
  bf16x8 Af[2][4];
#pragma unroll
  for (int mt = 0; mt < 2; mt++)
#pragma unroll
    for (int ks = 0; ks < 4; ks++)
      Af[mt][ks] = *(const bf16x8*)&At[(wv * 32 + mt * 16 + row) * 136 + ks * 32 + quad * 8];

  floatx4 Oa[2][8];
#pragma unroll
  for (int mt = 0; mt < 2; mt++)
#pragma unroll
    for (int nt = 0; nt < 8; nt++) Oa[mt][nt] = (floatx4)0.f;

  const int wvb = wv * 32 * 72;
  for (int ch = 0; ch < 8; ch++) {
    // GEMM1 (H^T): M = 64 hidden (4 tiles), N = 32 tokens (2 tiles)
    floatx4 Ha[4][2];
#pragma unroll
    for (int nt = 0; nt < 4; nt++)
#pragma unroll
      for (int mt = 0; mt < 2; mt++) Ha[nt][mt] = (floatx4)0.f;
#pragma unroll
    for (int nt = 0; nt < 4; nt++) {
      int ht = ch * 4 + nt;
#pragma unroll
      for (int ks = 0; ks < 4; ks++) {
        bf16x8 Wf = *(const bf16x8*)&w1b[(long)(((ht * 4 + ks) << 6) + lane) * 8];
        Ha[nt][0] = __builtin_amdgcn_mfma_f32_16x16x32_bf16(Wf, Af[0][ks], Ha[nt][0], 0, 0, 0);
        Ha[nt][1] = __builtin_amdgcn_mfma_f32_16x16x32_bf16(Wf, Af[1][ks], Ha[nt][1], 0, 0, 0);
      }
    }
    // epilogue: h = nt*16 + quad*4 + r (contiguous in r), tok = mt*16 + row
#pragma unroll
    for (int nt = 0; nt < 4; nt++) {
      float4 bb = *(const float4*)&b1[ch * 64 + nt * 16 + quad * 4];
#pragma unroll
      for (int mt = 0; mt < 2; mt++) {
        us4 hv;
        hv[0] = f2us(gelu_fast(Ha[nt][mt][0] + bb.x));
        hv[1] = f2us(gelu_fast(Ha[nt][mt][1] + bb.y));
        hv[2] = f2us(gelu_fast(Ha[nt][mt][2] + bb.z));
        hv[3] = f2us(gelu_fast(Ha[nt][mt][3] + bb.w));
        *(us4*)&Hs[wvb + (mt * 16 + row) * 72 + nt * 16 + quad * 4] = hv;
      }
    }
    __syncthreads();  // phase-lock waves (scheduling aid; Hs is per-wave)
    // GEMM2: O += H[32 tok x 64 h] x W2[64 h x 128 c]
    bf16x8 A2[2][2];
#pragma unroll
    for (int mt = 0; mt < 2; mt++)
#pragma unroll
      for (int ks = 0; ks < 2; ks++)
        A2[mt][ks] = *(const bf16x8*)&Hs[wvb + (mt * 16 + row) * 72 + ks * 32 + quad * 8];
#pragma unroll
    for (int nt = 0; nt < 8; nt++) {
#pragma unroll
      for (int ks = 0; ks < 2; ks++) {
        bf16x8 Bf = *(const bf16x8*)&w2b[(long)(((nt * 16 + ch * 2 + ks) << 6) + lane) * 8];
        Oa[0][nt] = __builtin_amdgcn_mfma_f32_16x16x32_bf16(A2[0][ks], Bf, Oa[0][nt], 0, 0, 0);
        Oa[1][nt] = __builtin_amdgcn_mfma_f32_16x16x32_bf16(A2[1][ks], Bf, Oa[1][nt], 0, 0, 0);
      }
    }
    __syncthreads();
  }
  // final epilogue: +b2, store [c][tok] fp32, accumulate bn2 partials
#pragma unroll
  for (int nt = 0; nt < 8; nt++) {
    int c = nt * 16 + row;
    float bb = b2[c];
    long op = base + (long)c * HWW + wv * 32 + quad * 4;
    float s = 0.f, s2 = 0.f;
#pragma unroll
    for (int mt = 0; mt < 2; mt++) {
      floatx4 vv = Oa[mt][nt];
      vv[0] += bb; vv[1] += bb; vv[2] += bb; vv[3] += bb;
      *(floatx4*)&tmid[op + mt * 16] = vv;
      s += vv[0] + vv[1] + vv[2] + vv[3];
      s2 += vv[0] * vv[0] + vv[1] * vv[1] + vv[2] * vv[2] + vv[3] * vv[3];
    }
    atomicAdd(&ps[c], s);
    atomicAdd(&ps2[c], s2);
  }
  __syncthreads();
  if (tid < 128) {
    atomicAdd(&part2[tid], ps[tid]);
    atomicAdd(&part2[128 + tid], ps2[tid]);
  }
}

// ---------------- Kernel H: bn2 + residual + gelu (stats2b fused) ---------
__global__ __launch_bounds__(256) void k_final(
    const float* __restrict__ x, const float* __restrict__ part2,
    const float* __restrict__ g2, const float* __restrict__ b2n,
    float* __restrict__ out) {
  long e4 = (long)blockIdx.x * 256 + threadIdx.x;
  int c = (int)((e4 >> 12) & 127);
  float mu = part2[c] * (1.f / 65536.f);
  float var = part2[128 + c] * (1.f / 65536.f) - mu * mu;
  float sc = rsqrtf(var + 1e-5f) * g2[c];
  float sh = b2n[c] - mu * sc;
  float4 o = *(float4*)&out[e4 * 4];
  float4 xv = *(const float4*)&x[e4 * 4];
  o.x = gelu_fast(xv.x + o.x * sc + sh);
  o.y = gelu_fast(xv.y + o.y * sc + sh);
  o.z = gelu_fast(xv.z + o.z * sc + sh);
  o.w = gelu_fast(xv.w + o.w * sc + sh);
  *(float4*)&out[e4 * 4] = o;
}

extern "C" void kernel_launch(void* const* d_in, const int* in_sizes, int n_in,
                              void* d_out, int out_size, void* d_ws, size_t ws_size,
                              hipStream_t stream) {
  const float* x        = (const float*)d_in[0];
  const float* offset_w = (const float*)d_in[1];
  const float* offset_b = (const float*)d_in[2];
  const float* deform_w = (const float*)d_in[3];
  const float* dw_w     = (const float*)d_in[4];
  const float* dw_b     = (const float*)d_in[5];
  const float* dw2_w    = (const float*)d_in[6];
  const float* dw2_b    = (const float*)d_in[7];
  const float* bn1_g    = (const float*)d_in[8];
  const float* bn1_b    = (const float*)d_in[9];
  const float* w1       = (const float*)d_in[10];
  const float* b1       = (const float*)d_in[11];
  const float* w2       = (const float*)d_in[12];
  const float* b2       = (const float*)d_in[13];
  const float* bn2_g    = (const float*)d_in[14];
  const float* bn2_b    = (const float*)d_in[15];
  float* out = (float*)d_out;

  float* ws    = (float*)d_ws;
  float* off   = ws;                       // 1,179,648 f
  float* ybuf  = ws + 1179648;             // 8,388,608 f
  unsigned short* w1b = (unsigned short*)(ws + 9568768);  // 65,536 us
  unsigned short* w2b = (unsigned short*)(ws + 9601536);  // 65,536 us
  float* part  = ws + 9634304;             // 1,024 f (bn1 partials)
  float* xt    = ws + 9635328;             // 2,097,152 f
  unsigned short* wob = (unsigned short*)(ws + 11732480); // 9,216 us
  unsigned short* w3b = (unsigned short*)(ws + 11737088); // 9,216 us
  unsigned short* xp  = (unsigned short*)(ws + 11741696); // 4,460,544 us
  unsigned short* xp0 = xp;
  unsigned short* xp1 = xp + (long)4 * PREC * 32;
  float* part2 = ws + 13971968;            // 256 f (atomic bn2 accumulators)
  float* tmid  = out;

  k_prep<<<107, 256, 0, stream>>>(xp, part2, w1, w2, w1b, w2b,
                                  offset_w, dw2_w, wob, w3b);
  k_pack<<<2048, 256, 0, stream>>>(x, xp, xt);
  k_conv3<<<1024, 256, 0, stream>>>(xp0, wob, offset_b, off, xp1, w3b, dw2_b, ybuf);
  k_dfw<<<2560, 256, 0, stream>>>(xt, off, deform_w, x, dw_w, dw_b, ybuf);
  k_stats1<<<512, 256, 0, stream>>>(ybuf, part);
  k_mlp_mfma<<<512, 256, 0, stream>>>(ybuf, part, bn1_g, bn1_b, w1b, b1, w2b, b2, tmid, part2);
  k_final<<<8192, 256, 0, stream>>>(x, part2, bn2_g, bn2_b, out);
}